// Round 8
// baseline (1750.623 us; speedup 1.0000x reference)
//
#include <hip/hip_runtime.h>
#include <hip/hip_bf16.h>

typedef unsigned int u32;
typedef unsigned short u16;
typedef __attribute__((ext_vector_type(8))) short bf16x8;   // 8 bf16 = 4 VGPRs
typedef __attribute__((ext_vector_type(4))) float f32x4;

#define DEVI __device__ __forceinline__

constexpr int AG = 8, H = 100, W = 352, HP = 102, WP = 354;
constexpr int HWp = H * W;          // 35200
constexpr int NB = 2 * WP + 2 * H;  // 908 border pixels per agent

DEVI u16 f2bf(float f) {
  __hip_bfloat16 h = __float2bfloat16(f);
  return *reinterpret_cast<u16*>(&h);
}
DEVI float bf2f(u16 v) { return __uint_as_float(((u32)v) << 16); }

// interleaved channel order within each 32-block: stored 8v+j <-> logical
// {4v+j (j<4), 16+4v+(j-4) (j>=4)} so one 16B unit = one MFMA k-fragment.
DEVI int chperm(int j) { int v = j >> 3, r = j & 7; return (r < 4) ? 4 * v + r : 16 + 4 * v + (r - 4); }
DEVI int chlog(int c) { return (c & ~31) + chperm(c & 31); }

typedef __attribute__((address_space(1))) const u32 as1c_u32;
typedef __attribute__((address_space(3))) u32 as3_u32;
DEVI void gload16(const u16* g, u16* l) {
  __builtin_amdgcn_global_load_lds((as1c_u32*)(const void*)g, (as3_u32*)(void*)l, 16, 0, 0);
}

template <int N> DEVI void waitcnt_vm() {
  if constexpr (N == 0) asm volatile("s_waitcnt vmcnt(0)" ::: "memory");
  else if constexpr (N == 6) asm volatile("s_waitcnt vmcnt(6)" ::: "memory");
  else if constexpr (N == 8) asm volatile("s_waitcnt vmcnt(8)" ::: "memory");
  else if constexpr (N == 12) asm volatile("s_waitcnt vmcnt(12)" ::: "memory");
  else if constexpr (N == 16) asm volatile("s_waitcnt vmcnt(16)" ::: "memory");
}

// ---------------------------------------------------------------------------
// feature slice fp32 NCHW -> padded NHWC(permuted) bf16 interior, via LDS
// transpose. grid: aloc*H*11 blocks; block 256 thr; tile = (a,h) x 32w x 64c.
__global__ void convert_feat(const float* __restrict__ f, u16* __restrict__ dst) {
  __shared__ float t32[64][33];
  int blk = blockIdx.x;
  int wseg = blk % 11;
  int rest = blk / 11;
  int h = rest % H;
  int a = rest / H;
  int t = threadIdx.x;
  int wbase = wseg * 32;
  {
    int w = t & 31;
    int c0 = (t >> 5) * 8;
#pragma unroll
    for (int i = 0; i < 8; ++i) {
      int lc = c0 + i;
      t32[lc][w] = f[((size_t)(a * 64 + lc) * H + h) * W + wbase + w];
    }
  }
  __syncthreads();
  int p = t >> 3;
  int cs = (t & 7) * 8;
  u16 tmp[8];
#pragma unroll
  for (int j = 0; j < 8; ++j) {
    int c = cs + j;
    int lc = (c & 32) + chperm(c & 31);
    tmp[j] = f2bf(t32[lc][p]);
  }
  size_t ob = ((size_t)(a * HP + h + 1) * WP + (wbase + p + 1)) * 64 + cs;
  *reinterpret_cast<uint4*>(dst + ob) = *reinterpret_cast<uint4*>(tmp);
}

// zero the 1-pixel border of a padded NHWC buffer with C channels, nA agents
template <int C>
__global__ void zero_border(u16* __restrict__ buf, int nA) {
  constexpr int CH = C / 8;
  int idx = blockIdx.x * 256 + threadIdx.x;
  int pix = idx / CH;
  int cc = (idx - pix * CH) * 8;
  if (pix >= nA * NB) return;
  int a = pix / NB;
  int b = pix - a * NB;
  int h, w;
  if (b < WP) { h = 0; w = b; }
  else if (b < 2 * WP) { h = HP - 1; w = b - WP; }
  else {
    int bb = b - 2 * WP;
    int bb2 = (bb < H) ? bb : bb - H;
    h = 1 + bb2;
    w = (bb < H) ? 0 : (WP - 1);
  }
  size_t off = ((size_t)(a * HP + h) * WP + w) * C + cc;
  *reinterpret_cast<uint4*>(buf + off) = make_uint4(0u, 0u, 0u, 0u);
}

// w [O][I][kh][kw] fp32 -> rp[s=t*KB+kb][r:O][u:8][jj:8] bf16 with the LDS
// row-XOR swizzle baked in: stored (r,u) holds logical unit lu = u^(r&7).
__global__ void repack_w(const float* __restrict__ w, u16* __restrict__ rp,
                         int O, int I, int taps) {
  int idx = blockIdx.x * 256 + threadIdx.x;
  int total = O * I * taps;
  if (idx >= total) return;
  int jj = idx & 7;
  int u = (idx >> 3) & 7;
  int r = (idx >> 6) % O;
  int s = idx / (O * 64);
  int KB = I >> 6;
  int kb = s % KB;
  int t = s / KB;
  int lu = u ^ (r & 7);
  int g = lu & 3, j32 = lu >> 2;
  int cp = (jj < 4) ? 4 * g + jj : 16 + 4 * g + (jj - 4);
  int i = kb * 64 + j32 * 32 + cp;
  int o = (r & ~31) + chperm(r & 31);
  rp[idx] = f2bf(w[((size_t)o * I + i) * taps + t]);
}

// ---------------------------------------------------------------------------
// Implicit-GEMM conv, BK=64, BN=COUT. NBUF-rotating LDS (2 or 3) with
// full-K-step staging and counted vmcnt (T4): tile-s loads get NBUF-1 full
// K-steps of flight. 2 barriers per K-step. setprio around MFMA (T5).
template <int CIN, int BN, int TAPS, int NBUF>
__global__ __launch_bounds__(BN * 2, 2) void conv_k(
    const u16* __restrict__ in, const u16* __restrict__ wrp,
    const float* __restrict__ bias, u16* __restrict__ out,
    int outHp, int outWp, int outPad) {
  constexpr int BM = 128, BK = 64;
  constexpr int KB = CIN / BK;         // 1,2,4
  constexpr int KS = TAPS * KB;
  constexpr int NT = BN * 2;           // threads
  constexpr int WN = BN / 64;          // waves along N
  constexpr int ACH = 1024 / NT;       // A chunks/thread (4 or 2)
  constexpr int BCH = 4;               // B chunks/thread
  constexpr int F = ACH + BCH;         // loads/thread per K-step (6 or 8)
  constexpr int ASZ = BM * BK;         // elements per A buffer
  constexpr int BSZ = BN * BK;
  __shared__ u16 smem[NBUF * (ASZ + BSZ)];  // 64 KB (2-buf) / 144 KB (3-buf)

  const int tid = threadIdx.x;
  const int lane = tid & 63;
  const int wid = tid >> 6;
  const int wr = wid / WN;             // 0..1
  const int wc = wid % WN;

  // bijective XCD-aware remap (m204)
  int nwg = gridDim.x;
  int orig = blockIdx.x;
  int q = nwg >> 3, r8 = nwg & 7;
  int xcd = orig & 7, pos = orig >> 3;
  int wg = (xcd < r8 ? xcd * (q + 1) : r8 * (q + 1) + (xcd - r8) * q) + pos;
  const int n0 = wg * BM;

  // A staging addresses: chunk c = p*8+u; global supplies lu = u^(p&7)
  int aoff[ACH];
#pragma unroll
  for (int i = 0; i < ACH; ++i) {
    int c = tid + i * NT;
    int p = c >> 3, u = c & 7;
    int lu = u ^ (p & 7);
    int np2 = n0 + p;
    int a = np2 / HWp;
    int r1 = np2 - a * HWp;
    int h = r1 / W;
    int w = r1 - h * W;
    aoff[i] = ((a * HP + h + 1) * WP + (w + 1)) * CIN + lu * 8;
  }

  f32x4 acc[4][4];
#pragma unroll
  for (int m = 0; m < 4; ++m)
#pragma unroll
    for (int n = 0; n < 4; ++n) acc[m][n] = f32x4{0.f, 0.f, 0.f, 0.f};

  const int g = lane >> 4;
  const int arow = lane & 15;
  const int fk = arow & 7;

  // stage all of K-step s into buffer s % NBUF (F loads/thread)
  auto stage = [&](int s) {
    int par = s % NBUF;
    u16* Ad = smem + par * ASZ;
    u16* Bd = smem + NBUF * ASZ + par * BSZ;
    int t = (TAPS == 1) ? 0 : s / KB;
    int kb = (TAPS == 1) ? s : s - t * KB;
    int doff = kb * BK + ((TAPS == 9) ? ((t / 3 - 1) * WP + (t % 3 - 1)) * CIN : 0);
    const u16* wtile = wrp + (size_t)s * BSZ;
#pragma unroll
    for (int i = 0; i < ACH; ++i)
      gload16(in + aoff[i] + doff, Ad + (tid + i * NT) * 8);
#pragma unroll
    for (int i = 0; i < BCH; ++i)
      gload16(wtile + (tid + i * NT) * 8, Bd + (tid + i * NT) * 8);
  };

  stage(0);
  if constexpr (NBUF == 3) stage(1);

  for (int s = 0; s < KS; ++s) {
    int par = s % NBUF;
    const u16* Ab = smem + par * ASZ;
    const u16* Bb = smem + NBUF * ASZ + par * BSZ;
    if (s + NBUF - 1 < KS) stage(s + NBUF - 1);  // deepest prefetch
    // counted wait: only tile-s loads (oldest) must be complete
    if constexpr (NBUF == 3) {
      if (s + 2 < KS) waitcnt_vm<2 * F>();
      else if (s + 1 < KS) waitcnt_vm<F>();
      else waitcnt_vm<0>();
    } else {
      if (s + 1 < KS) waitcnt_vm<F>();
      else waitcnt_vm<0>();
    }
    __builtin_amdgcn_s_barrier();      // tile s visible to all waves

#pragma unroll
    for (int j = 0; j < 2; ++j) {
      bf16x8 af[4], bfr[4];
#pragma unroll
      for (int m = 0; m < 4; ++m)
        af[m] = *reinterpret_cast<const bf16x8*>(
            Ab + (wr * 64 + m * 16 + arow) * 64 + (((j * 4 + g) ^ fk) << 3));
#pragma unroll
      for (int n = 0; n < 4; ++n)
        bfr[n] = *reinterpret_cast<const bf16x8*>(
            Bb + (wc * 64 + n * 16 + arow) * 64 + (((j * 4 + g) ^ fk) << 3));
      __builtin_amdgcn_s_setprio(1);
#pragma unroll
      for (int m = 0; m < 4; ++m)
#pragma unroll
        for (int n = 0; n < 4; ++n)
          acc[m][n] = __builtin_amdgcn_mfma_f32_16x16x32_bf16(af[m], bfr[n], acc[m][n], 0, 0, 0);
      __builtin_amdgcn_s_setprio(0);
    }
    __builtin_amdgcn_s_barrier();      // all reads of this buffer done
  }

  // ---- epilogue: bias+relu -> per-wave 4KB LDS tile (2 passes of 32 px)
  __syncthreads();
  float bs[4];
#pragma unroll
  for (int n = 0; n < 4; ++n) bs[n] = bias[chlog(wc * 64 + n * 16 + arow)];
  u16* et = smem + wid * 2048;  // 32 px x 64 ch per wave
#pragma unroll
  for (int pp = 0; pp < 2; ++pp) {
    if (pp) __syncthreads();
#pragma unroll
    for (int mm = 0; mm < 2; ++mm) {
      int m = pp * 2 + mm;
#pragma unroll
      for (int rg = 0; rg < 4; ++rg) {
        int row = mm * 16 + g * 4 + rg;  // 0..31; (row>>2)&3 == g
#pragma unroll
        for (int n = 0; n < 4; ++n) {
          int col = (n * 16 + arow) ^ (g << 4);
          et[row * 64 + col] = f2bf(fmaxf(acc[m][n][rg] + bs[n], 0.f));
        }
      }
    }
    __syncthreads();
#pragma unroll
    for (int jj = 0; jj < 4; ++jj) {
      int p = jj * 8 + (lane >> 3);  // 0..31
      int un = lane & 7;
      int su = un ^ (((p >> 2) & 3) << 1);
      uint4 qv = *reinterpret_cast<const uint4*>(et + p * 64 + su * 8);
      int np2 = n0 + wr * 64 + pp * 32 + p;
      int a = np2 / HWp;
      int r1 = np2 - a * HWp;
      int h = r1 / W;
      int w = r1 - h * W;
      size_t ob = ((size_t)(a * outHp + h + outPad) * outWp + (w + outPad)) * BN +
                  wc * 64 + un * 8;
      *reinterpret_cast<uint4*>(out + ob) = qv;
    }
  }
}

// ---------------------------------------------------------------------------
// box-mean pooling over y slice [nA][100][352][256] bf16(permuted) -> desc fp32
__global__ void pool_k(const u16* __restrict__ y, const int* __restrict__ boxes,
                       float* __restrict__ desc) {
  int blk = blockIdx.x;  // local: a*50 + k
  const int* bx = boxes + blk * 4;
  int a = blk / 50;
  int l = bx[0], r = bx[1], u = bx[2], d = bx[3];
  int c = threadIdx.x;
  float s = 0.f;
  for (int h = u; h < d; ++h) {
    const u16* row = y + ((size_t)(a * H + h) * W) * 256 + c;
    for (int w2 = l; w2 < r; ++w2) s += bf2f(row[(size_t)w2 * 256]);
  }
  desc[(size_t)blk * 256 + chlog(c)] = s / (float)((d - u) * (r - l));
}

// ---------------------------------------------------------------------------
extern "C" void kernel_launch(void* const* d_in, const int* in_sizes, int n_in,
                              void* d_out, int out_size, void* d_ws, size_t ws_size,
                              hipStream_t stream) {
  const float* feature = (const float*)d_in[0];
  const int* boxes = (const int*)d_in[1];
  const float* w1a = (const float*)d_in[2];
  const float* b1a = (const float*)d_in[3];
  const float* w1b = (const float*)d_in[4];
  const float* b1b = (const float*)d_in[5];
  const float* w2a = (const float*)d_in[6];
  const float* b2a = (const float*)d_in[7];
  const float* w2b = (const float*)d_in[8];
  const float* b2b = (const float*)d_in[9];
  const float* w3a = (const float*)d_in[10];
  const float* b3a = (const float*)d_in[11];
  const float* w3b = (const float*)d_in[12];
  const float* b3b = (const float*)d_in[13];
  const float* wDa = (const float*)d_in[14];
  const float* bDa = (const float*)d_in[15];
  const float* wDb = (const float*)d_in[16];
  const float* bDb = (const float*)d_in[17];
  const float* wF = (const float*)d_in[18];
  const float* bF = (const float*)d_in[19];

  const size_t WB = (size_t)2 * ((size_t)9 * 64 * 128 + 3 * 9 * 128 * 128 +
                                 (size_t)9 * 128 * 256 + 2 * 9 * 256 * 256 +
                                 2 * 256 * 256);  // repacked weight bytes
  // per-agent activation bytes: (128+128+256+256+64) ch * HP*WP * 2B
  const size_t PER_A = (size_t)832 * HP * WP * 2;
  int aloc = (ws_size >= 4 * PER_A + WB) ? 4 : 2;  // agents per slice
  const int npixl = aloc * HWp;

  char* ws = (char*)d_ws;
  const size_t SZ128 = (size_t)aloc * HP * WP * 128 * 2;
  const size_t SZ256 = (size_t)aloc * HP * WP * 256 * 2;
  const size_t SZ64  = (size_t)aloc * HP * WP * 64 * 2;
  u16* X  = (u16*)(ws);
  u16* Y  = (u16*)(ws + SZ128);
  u16* S0 = (u16*)(ws + 2 * SZ128);
  u16* S1 = (u16*)(ws + 2 * SZ128 + SZ256);
  u16* in64 = (u16*)(ws + 2 * SZ128 + 2 * SZ256);
  u16* rp = (u16*)(ws + 2 * SZ128 + 2 * SZ256 + SZ64);

  const size_t o1a = 0;
  const size_t o1b = o1a + (size_t)9 * 64 * 128;
  const size_t o2a = o1b + (size_t)9 * 128 * 128;
  const size_t o2b = o2a + (size_t)9 * 128 * 128;
  const size_t o3a = o2b + (size_t)9 * 128 * 128;
  const size_t o3b = o3a + (size_t)9 * 128 * 256;
  const size_t oDa = o3b + (size_t)9 * 256 * 256;
  const size_t oDb = oDa + (size_t)9 * 256 * 256;
  const size_t oF = oDb + (size_t)256 * 256;

  auto rpk = [&](const float* wsrc, size_t off, int O, int I, int taps) {
    int total = O * I * taps;
    repack_w<<<(total + 255) / 256, 256, 0, stream>>>(wsrc, rp + off, O, I, taps);
  };
  rpk(w1a, o1a, 128, 64, 9);
  rpk(w1b, o1b, 128, 128, 9);
  rpk(w2a, o2a, 128, 128, 9);
  rpk(w2b, o2b, 128, 128, 9);
  rpk(w3a, o3a, 256, 128, 9);
  rpk(w3b, o3b, 256, 256, 9);
  rpk(wDa, oDa, 256, 256, 9);
  rpk(wDb, oDb, 256, 256, 1);
  rpk(wF, oF, 256, 256, 1);

  // borders never corrupted: zero once per call
  zero_border<64><<<(aloc * NB * 8 + 255) / 256, 256, 0, stream>>>(in64, aloc);
  zero_border<128><<<(aloc * NB * 16 + 255) / 256, 256, 0, stream>>>(X, aloc);
  zero_border<128><<<(aloc * NB * 16 + 255) / 256, 256, 0, stream>>>(Y, aloc);
  zero_border<256><<<(aloc * NB * 32 + 255) / 256, 256, 0, stream>>>(S1, aloc);

  const int G = npixl / 128;  // 550 or 1100
  for (int a0 = 0; a0 < AG; a0 += aloc) {
    // S0's padded border was overwritten by previous slice's unpadded convF
    zero_border<256><<<(aloc * NB * 32 + 255) / 256, 256, 0, stream>>>(S0, aloc);

    convert_feat<<<aloc * H * 11, 256, 0, stream>>>(
        feature + (size_t)a0 * 64 * H * W, in64);

    conv_k<64, 128, 9, 2><<<G, 256, 0, stream>>>(in64, rp + o1a, b1a, X, HP, WP, 1);
    conv_k<128, 128, 9, 2><<<G, 256, 0, stream>>>(X, rp + o1b, b1b, Y, HP, WP, 1);
    conv_k<128, 128, 9, 2><<<G, 256, 0, stream>>>(Y, rp + o2a, b2a, X, HP, WP, 1);
    conv_k<128, 128, 9, 2><<<G, 256, 0, stream>>>(X, rp + o2b, b2b, Y, HP, WP, 1);
    conv_k<128, 256, 9, 3><<<G, 512, 0, stream>>>(Y, rp + o3a, b3a, S0, HP, WP, 1);
    conv_k<256, 256, 9, 3><<<G, 512, 0, stream>>>(S0, rp + o3b, b3b, S1, HP, WP, 1);
    conv_k<256, 256, 9, 3><<<G, 512, 0, stream>>>(S1, rp + oDa, bDa, S0, HP, WP, 1);
    conv_k<256, 256, 1, 3><<<G, 512, 0, stream>>>(S0, rp + oDb, bDb, S1, HP, WP, 1);
    conv_k<256, 256, 1, 3><<<G, 512, 0, stream>>>(S1, rp + oF, bF, S0, H, W, 0);

    pool_k<<<aloc * 50, 256, 0, stream>>>(S0, boxes + (size_t)a0 * 50 * 4,
                                          ((float*)d_out) + (size_t)a0 * 50 * 256);
  }
}

// Round 9
// 1744.211 us; speedup vs baseline: 1.0037x; 1.0037x over previous
//
#include <hip/hip_runtime.h>
#include <hip/hip_bf16.h>

typedef unsigned int u32;
typedef unsigned short u16;
typedef __attribute__((ext_vector_type(8))) short bf16x8;   // 8 bf16 = 4 VGPRs
typedef __attribute__((ext_vector_type(4))) float f32x4;

#define DEVI __device__ __forceinline__

constexpr int AG = 8, H = 100, W = 352, HP = 102, WP = 354;
constexpr int HWp = H * W;          // 35200
constexpr int NB = 2 * WP + 2 * H;  // 908 border pixels per agent

DEVI u16 f2bf(float f) {
  __hip_bfloat16 h = __float2bfloat16(f);
  return *reinterpret_cast<u16*>(&h);
}
DEVI float bf2f(u16 v) { return __uint_as_float(((u32)v) << 16); }

// interleaved channel order within each 32-block: stored 8v+j <-> logical
// {4v+j (j<4), 16+4v+(j-4) (j>=4)} so one 16B unit = one MFMA k-fragment.
DEVI int chperm(int j) { int v = j >> 3, r = j & 7; return (r < 4) ? 4 * v + r : 16 + 4 * v + (r - 4); }
DEVI int chlog(int c) { return (c & ~31) + chperm(c & 31); }

typedef __attribute__((address_space(1))) const u32 as1c_u32;
typedef __attribute__((address_space(3))) u32 as3_u32;
DEVI void gload16(const u16* g, u16* l) {
  __builtin_amdgcn_global_load_lds((as1c_u32*)(const void*)g, (as3_u32*)(void*)l, 16, 0, 0);
}

template <int N> DEVI void waitcnt_vm() {
  if constexpr (N == 0) asm volatile("s_waitcnt vmcnt(0)" ::: "memory");
  else if constexpr (N == 3) asm volatile("s_waitcnt vmcnt(3)" ::: "memory");
  else if constexpr (N == 4) asm volatile("s_waitcnt vmcnt(4)" ::: "memory");
  else asm volatile("s_waitcnt vmcnt(0)" ::: "memory");
}

// ---------------------------------------------------------------------------
// feature slice fp32 NCHW -> padded NHWC(permuted) bf16 interior, via LDS
// transpose. grid: aloc*H*11 blocks; block 256 thr; tile = (a,h) x 32w x 64c.
__global__ void convert_feat(const float* __restrict__ f, u16* __restrict__ dst) {
  __shared__ float t32[64][33];
  int blk = blockIdx.x;
  int wseg = blk % 11;
  int rest = blk / 11;
  int h = rest % H;
  int a = rest / H;
  int t = threadIdx.x;
  int wbase = wseg * 32;
  {
    int w = t & 31;
    int c0 = (t >> 5) * 8;
#pragma unroll
    for (int i = 0; i < 8; ++i) {
      int lc = c0 + i;
      t32[lc][w] = f[((size_t)(a * 64 + lc) * H + h) * W + wbase + w];
    }
  }
  __syncthreads();
  int p = t >> 3;
  int cs = (t & 7) * 8;
  u16 tmp[8];
#pragma unroll
  for (int j = 0; j < 8; ++j) {
    int c = cs + j;
    int lc = (c & 32) + chperm(c & 31);
    tmp[j] = f2bf(t32[lc][p]);
  }
  size_t ob = ((size_t)(a * HP + h + 1) * WP + (wbase + p + 1)) * 64 + cs;
  *reinterpret_cast<uint4*>(dst + ob) = *reinterpret_cast<uint4*>(tmp);
}

// zero the 1-pixel border of a padded NHWC buffer with C channels, nA agents
template <int C>
__global__ void zero_border(u16* __restrict__ buf, int nA) {
  constexpr int CH = C / 8;
  int idx = blockIdx.x * 256 + threadIdx.x;
  int pix = idx / CH;
  int cc = (idx - pix * CH) * 8;
  if (pix >= nA * NB) return;
  int a = pix / NB;
  int b = pix - a * NB;
  int h, w;
  if (b < WP) { h = 0; w = b; }
  else if (b < 2 * WP) { h = HP - 1; w = b - WP; }
  else {
    int bb = b - 2 * WP;
    int bb2 = (bb < H) ? bb : bb - H;
    h = 1 + bb2;
    w = (bb < H) ? 0 : (WP - 1);
  }
  size_t off = ((size_t)(a * HP + h) * WP + w) * C + cc;
  *reinterpret_cast<uint4*>(buf + off) = make_uint4(0u, 0u, 0u, 0u);
}

// w [O][I][kh][kw] fp32 -> rp[s=t*KB+kb][r:O][u:8][jj:8] bf16 with the LDS
// row-XOR swizzle baked in: stored (r,u) holds logical unit lu = u^(r&7).
__global__ void repack_w(const float* __restrict__ w, u16* __restrict__ rp,
                         int O, int I, int taps) {
  int idx = blockIdx.x * 256 + threadIdx.x;
  int total = O * I * taps;
  if (idx >= total) return;
  int jj = idx & 7;
  int u = (idx >> 3) & 7;
  int r = (idx >> 6) % O;
  int s = idx / (O * 64);
  int KB = I >> 6;
  int kb = s % KB;
  int t = s / KB;
  int lu = u ^ (r & 7);
  int g = lu & 3, j32 = lu >> 2;
  int cp = (jj < 4) ? 4 * g + jj : 16 + 4 * g + (jj - 4);
  int i = kb * 64 + j32 * 32 + cp;
  int o = (r & ~31) + chperm(r & 31);
  rp[idx] = f2bf(w[((size_t)o * I + i) * taps + t]);
}

// ---------------------------------------------------------------------------
// Round-6 proven kernel (BN=128 layers): BK=64, dbuf, half-split staging,
// counted vmcnt, setprio. 2 barriers per K-step.
template <int CIN, int BN, int TAPS>
__global__ __launch_bounds__(BN * 2, 2) void conv_k(
    const u16* __restrict__ in, const u16* __restrict__ wrp,
    const float* __restrict__ bias, u16* __restrict__ out,
    int outHp, int outWp, int outPad) {
  constexpr int BM = 128, BK = 64;
  constexpr int KB = CIN / BK;
  constexpr int KS = TAPS * KB;
  constexpr int NT = BN * 2;
  constexpr int WN = BN / 64;
  constexpr int ACH = 1024 / NT;       // 4
  constexpr int AH = ACH / 2;          // 2
  constexpr int BH = 2;
  constexpr int HALF = AH + BH;        // 4
  constexpr int ASZ = BM * BK;
  constexpr int BSZ = BN * BK;
  __shared__ u16 smem[2 * (ASZ + BSZ)];

  const int tid = threadIdx.x;
  const int lane = tid & 63;
  const int wid = tid >> 6;
  const int wr = wid / WN;
  const int wc = wid % WN;

  int nwg = gridDim.x;
  int orig = blockIdx.x;
  int q = nwg >> 3, r8 = nwg & 7;
  int xcd = orig & 7, pos = orig >> 3;
  int wg = (xcd < r8 ? xcd * (q + 1) : r8 * (q + 1) + (xcd - r8) * q) + pos;
  const int n0 = wg * BM;

  int aoff[ACH];
#pragma unroll
  for (int i = 0; i < ACH; ++i) {
    int c = tid + i * NT;
    int p = c >> 3, u = c & 7;
    int lu = u ^ (p & 7);
    int np2 = n0 + p;
    int a = np2 / HWp;
    int r1 = np2 - a * HWp;
    int h = r1 / W;
    int w = r1 - h * W;
    aoff[i] = ((a * HP + h + 1) * WP + (w + 1)) * CIN + lu * 8;
  }

  f32x4 acc[4][4];
#pragma unroll
  for (int m = 0; m < 4; ++m)
#pragma unroll
    for (int n = 0; n < 4; ++n) acc[m][n] = f32x4{0.f, 0.f, 0.f, 0.f};

  const int g = lane >> 4;
  const int arow = lane & 15;
  const int fk = arow & 7;

  auto stage = [&](int s, int h) {
    int par = s & 1;
    u16* Ad = smem + par * ASZ;
    u16* Bd = smem + 2 * ASZ + par * BSZ;
    int t = (TAPS == 1) ? 0 : s / KB;
    int kb = (TAPS == 1) ? s : s - t * KB;
    int doff = kb * BK + ((TAPS == 9) ? ((t / 3 - 1) * WP + (t % 3 - 1)) * CIN : 0);
    const u16* wtile = wrp + (size_t)s * BSZ;
#pragma unroll
    for (int i = h * AH; i < h * AH + AH; ++i)
      gload16(in + aoff[i] + doff, Ad + (tid + i * NT) * 8);
#pragma unroll
    for (int i = h * BH; i < h * BH + BH; ++i)
      gload16(wtile + (tid + i * NT) * 8, Bd + (tid + i * NT) * 8);
  };

  stage(0, 0);
  stage(0, 1);

  for (int s = 0; s < KS; ++s) {
    int par = s & 1;
    const u16* Ab = smem + par * ASZ;
    const u16* Bb = smem + 2 * ASZ + par * BSZ;
    if (s + 1 < KS) {
      stage(s + 1, 0);
      waitcnt_vm<HALF>();
    } else {
      waitcnt_vm<0>();
    }
    __builtin_amdgcn_s_barrier();

#pragma unroll
    for (int j = 0; j < 2; ++j) {
      bf16x8 af[4], bfr[4];
#pragma unroll
      for (int m = 0; m < 4; ++m)
        af[m] = *reinterpret_cast<const bf16x8*>(
            Ab + (wr * 64 + m * 16 + arow) * 64 + (((j * 4 + g) ^ fk) << 3));
#pragma unroll
      for (int n = 0; n < 4; ++n)
        bfr[n] = *reinterpret_cast<const bf16x8*>(
            Bb + (wc * 64 + n * 16 + arow) * 64 + (((j * 4 + g) ^ fk) << 3));
      __builtin_amdgcn_s_setprio(1);
#pragma unroll
      for (int m = 0; m < 4; ++m)
#pragma unroll
        for (int n = 0; n < 4; ++n)
          acc[m][n] = __builtin_amdgcn_mfma_f32_16x16x32_bf16(af[m], bfr[n], acc[m][n], 0, 0, 0);
      __builtin_amdgcn_s_setprio(0);
      if (j == 0 && s + 1 < KS) stage(s + 1, 1);
    }
    __builtin_amdgcn_s_barrier();
  }

  __syncthreads();
  float bs[4];
#pragma unroll
  for (int n = 0; n < 4; ++n) bs[n] = bias[chlog(wc * 64 + n * 16 + arow)];
  u16* et = smem + wid * 2048;
#pragma unroll
  for (int pp = 0; pp < 2; ++pp) {
    if (pp) __syncthreads();
#pragma unroll
    for (int mm = 0; mm < 2; ++mm) {
      int m = pp * 2 + mm;
#pragma unroll
      for (int rg = 0; rg < 4; ++rg) {
        int row = mm * 16 + g * 4 + rg;
#pragma unroll
        for (int n = 0; n < 4; ++n) {
          int col = (n * 16 + arow) ^ (g << 4);
          et[row * 64 + col] = f2bf(fmaxf(acc[m][n][rg] + bs[n], 0.f));
        }
      }
    }
    __syncthreads();
#pragma unroll
    for (int jj = 0; jj < 4; ++jj) {
      int p = jj * 8 + (lane >> 3);
      int un = lane & 7;
      int su = un ^ (((p >> 2) & 3) << 1);
      uint4 qv = *reinterpret_cast<const uint4*>(et + p * 64 + su * 8);
      int np2 = n0 + wr * 64 + pp * 32 + p;
      int a = np2 / HWp;
      int r1 = np2 - a * HWp;
      int h = r1 / W;
      int w = r1 - h * W;
      size_t ob = ((size_t)(a * outHp + h + outPad) * outWp + (w + outPad)) * BN +
                  wc * 64 + un * 8;
      *reinterpret_cast<uint4*>(out + ob) = qv;
    }
  }
}

// ---------------------------------------------------------------------------
// m201-style 8-wave 256x256 4-phase kernel for BN=256 layers.
// Per-wave 128x64 output (acc 8x4 f32x4). Per K-step: 4 barrier-pair phases,
// 16 MFMA each; staging of tile s+1 front-loaded into phases 0-1; vmcnt(0)
// at step end has ~3 phases of flight.
template <int CIN, int TAPS>
__global__ __launch_bounds__(512, 2) void conv8(
    const u16* __restrict__ in, const u16* __restrict__ wrp,
    const float* __restrict__ bias, u16* __restrict__ out,
    int outHp, int outWp, int outPad) {
  constexpr int BM = 256, BN = 256, BK = 64;
  constexpr int KB = CIN / BK;         // 2 or 4
  constexpr int KS = TAPS * KB;
  constexpr int ASZ = BM * BK;         // 16384 elems (32 KB)
  constexpr int BSZ = BN * BK;
  __shared__ u16 smem[2 * (ASZ + BSZ)];  // 128 KB

  const int tid = threadIdx.x;
  const int lane = tid & 63;
  const int wid = tid >> 6;            // 0..7
  const int wr = wid >> 2;             // 0..1 (M)
  const int wc = wid & 3;              // 0..3 (N)

  int nwg = gridDim.x;
  int orig = blockIdx.x;
  int q = nwg >> 3, r8 = nwg & 7;
  int xcd = orig & 7, pos = orig >> 3;
  int wg = (xcd < r8 ? xcd * (q + 1) : r8 * (q + 1) + (xcd - r8) * q) + pos;
  const int n0 = wg * BM;

  // A staging: 2048 chunks, 4/thread; global supplies lu = u^(p&7)
  int aoff[4];
#pragma unroll
  for (int i = 0; i < 4; ++i) {
    int c = tid + i * 512;
    int p = c >> 3, u = c & 7;
    int lu = u ^ (p & 7);
    int np2 = n0 + p;
    int a = np2 / HWp;
    int r1 = np2 - a * HWp;
    int h = r1 / W;
    int w = r1 - h * W;
    aoff[i] = ((a * HP + h + 1) * WP + (w + 1)) * CIN + lu * 8;
  }

  f32x4 acc[8][4];
#pragma unroll
  for (int m = 0; m < 8; ++m)
#pragma unroll
    for (int n = 0; n < 4; ++n) acc[m][n] = f32x4{0.f, 0.f, 0.f, 0.f};

  const int g = lane >> 4;
  const int arow = lane & 15;
  const int fk = arow & 7;

  auto stageA = [&](int s) {
    u16* Ad = smem + (s & 1) * ASZ;
    int t = (TAPS == 1) ? 0 : s / KB;
    int kb = (TAPS == 1) ? s : s - t * KB;
    int doff = kb * BK + ((TAPS == 9) ? ((t / 3 - 1) * WP + (t % 3 - 1)) * CIN : 0);
#pragma unroll
    for (int i = 0; i < 4; ++i)
      gload16(in + aoff[i] + doff, Ad + (tid + i * 512) * 8);
  };
  auto stageB = [&](int s) {
    u16* Bd = smem + 2 * ASZ + (s & 1) * BSZ;
    const u16* wtile = wrp + (size_t)s * BSZ;
#pragma unroll
    for (int i = 0; i < 4; ++i)
      gload16(wtile + (tid + i * 512) * 8, Bd + (tid + i * 512) * 8);
  };

  stageA(0);
  stageB(0);
  waitcnt_vm<0>();
  __builtin_amdgcn_s_barrier();

  for (int s = 0; s < KS; ++s) {
    const int par = s & 1;
    const u16* Ab = smem + par * ASZ;
    const u16* Bb = smem + 2 * ASZ + par * BSZ;
    const bool pf = (s + 1 < KS);
    bf16x8 aq[4][2], bq[4][2];

    // ---- phase 0: read A(mh0)+B(nh0); stage next A; MFMA mh0 x nh0
#pragma unroll
    for (int mf = 0; mf < 4; ++mf)
#pragma unroll
      for (int ks = 0; ks < 2; ++ks)
        aq[mf][ks] = *reinterpret_cast<const bf16x8*>(
            Ab + (wr * 128 + mf * 16 + arow) * 64 + (((ks * 4 + g) ^ fk) << 3));
#pragma unroll
    for (int nf = 0; nf < 2; ++nf)
#pragma unroll
      for (int ks = 0; ks < 2; ++ks)
        bq[nf][ks] = *reinterpret_cast<const bf16x8*>(
            Bb + (wc * 64 + nf * 16 + arow) * 64 + (((ks * 4 + g) ^ fk) << 3));
    if (pf) stageA(s + 1);
    __builtin_amdgcn_s_barrier();
    __builtin_amdgcn_s_setprio(1);
#pragma unroll
    for (int ks = 0; ks < 2; ++ks)
#pragma unroll
      for (int mf = 0; mf < 4; ++mf)
#pragma unroll
        for (int nf = 0; nf < 2; ++nf)
          acc[mf][nf] = __builtin_amdgcn_mfma_f32_16x16x32_bf16(aq[mf][ks], bq[nf][ks], acc[mf][nf], 0, 0, 0);
    __builtin_amdgcn_s_setprio(0);
    __builtin_amdgcn_s_barrier();

    // ---- phase 1: read B(nh1); stage next B; MFMA mh0 x nh1
#pragma unroll
    for (int nf = 2; nf < 4; ++nf)
#pragma unroll
      for (int ks = 0; ks < 2; ++ks)
        bq[nf][ks] = *reinterpret_cast<const bf16x8*>(
            Bb + (wc * 64 + nf * 16 + arow) * 64 + (((ks * 4 + g) ^ fk) << 3));
    if (pf) stageB(s + 1);
    __builtin_amdgcn_s_barrier();
    __builtin_amdgcn_s_setprio(1);
#pragma unroll
    for (int ks = 0; ks < 2; ++ks)
#pragma unroll
      for (int mf = 0; mf < 4; ++mf)
#pragma unroll
        for (int nf = 2; nf < 4; ++nf)
          acc[mf][nf] = __builtin_amdgcn_mfma_f32_16x16x32_bf16(aq[mf][ks], bq[nf][ks], acc[mf][nf], 0, 0, 0);
    __builtin_amdgcn_s_setprio(0);
    __builtin_amdgcn_s_barrier();

    // ---- phase 2: read A(mh1); MFMA mh1 x nh1
#pragma unroll
    for (int mf = 0; mf < 4; ++mf)
#pragma unroll
      for (int ks = 0; ks < 2; ++ks)
        aq[mf][ks] = *reinterpret_cast<const bf16x8*>(
            Ab + (wr * 128 + 64 + mf * 16 + arow) * 64 + (((ks * 4 + g) ^ fk) << 3));
    __builtin_amdgcn_s_barrier();
    __builtin_amdgcn_s_setprio(1);
#pragma unroll
    for (int ks = 0; ks < 2; ++ks)
#pragma unroll
      for (int mf = 0; mf < 4; ++mf)
#pragma unroll
        for (int nf = 2; nf < 4; ++nf)
          acc[4 + mf][nf] = __builtin_amdgcn_mfma_f32_16x16x32_bf16(aq[mf][ks], bq[nf][ks], acc[4 + mf][nf], 0, 0, 0);
    __builtin_amdgcn_s_setprio(0);
    __builtin_amdgcn_s_barrier();

    // ---- phase 3: MFMA mh1 x nh0 (all operands register-resident)
    __builtin_amdgcn_s_setprio(1);
#pragma unroll
    for (int ks = 0; ks < 2; ++ks)
#pragma unroll
      for (int mf = 0; mf < 4; ++mf)
#pragma unroll
        for (int nf = 0; nf < 2; ++nf)
          acc[4 + mf][nf] = __builtin_amdgcn_mfma_f32_16x16x32_bf16(aq[mf][ks], bq[nf][ks], acc[4 + mf][nf], 0, 0, 0);
    __builtin_amdgcn_s_setprio(0);
    if (pf) waitcnt_vm<0>();  // next tile landed; loads had ~3 phases of flight
    __builtin_amdgcn_s_barrier();
  }

  // ---- epilogue: bias+relu -> per-wave 4KB LDS tile (4 passes of 32 px)
  __syncthreads();
  float bs[4];
#pragma unroll
  for (int n = 0; n < 4; ++n) bs[n] = bias[chlog(wc * 64 + n * 16 + arow)];
  u16* et = smem + wid * 2048;
#pragma unroll
  for (int pp = 0; pp < 4; ++pp) {
    if (pp) __syncthreads();
#pragma unroll
    for (int mm = 0; mm < 2; ++mm) {
      int m = pp * 2 + mm;
#pragma unroll
      for (int rg = 0; rg < 4; ++rg) {
        int row = mm * 16 + g * 4 + rg;
#pragma unroll
        for (int n = 0; n < 4; ++n) {
          int col = (n * 16 + arow) ^ (g << 4);
          et[row * 64 + col] = f2bf(fmaxf(acc[m][n][rg] + bs[n], 0.f));
        }
      }
    }
    __syncthreads();
#pragma unroll
    for (int jj = 0; jj < 4; ++jj) {
      int p = jj * 8 + (lane >> 3);
      int un = lane & 7;
      int su = un ^ (((p >> 2) & 3) << 1);
      uint4 qv = *reinterpret_cast<const uint4*>(et + p * 64 + su * 8);
      int np2 = n0 + wr * 128 + pp * 32 + p;
      int a = np2 / HWp;
      int r1 = np2 - a * HWp;
      int h = r1 / W;
      int w = r1 - h * W;
      size_t ob = ((size_t)(a * outHp + h + outPad) * outWp + (w + outPad)) * BN +
                  wc * 64 + un * 8;
      *reinterpret_cast<uint4*>(out + ob) = qv;
    }
  }
}

// ---------------------------------------------------------------------------
// box-mean pooling over y slice [nA][100][352][256] bf16(permuted) -> desc fp32
__global__ void pool_k(const u16* __restrict__ y, const int* __restrict__ boxes,
                       float* __restrict__ desc) {
  int blk = blockIdx.x;
  const int* bx = boxes + blk * 4;
  int a = blk / 50;
  int l = bx[0], r = bx[1], u = bx[2], d = bx[3];
  int c = threadIdx.x;
  float s = 0.f;
  for (int h = u; h < d; ++h) {
    const u16* row = y + ((size_t)(a * H + h) * W) * 256 + c;
    for (int w2 = l; w2 < r; ++w2) s += bf2f(row[(size_t)w2 * 256]);
  }
  desc[(size_t)blk * 256 + chlog(c)] = s / (float)((d - u) * (r - l));
}

// ---------------------------------------------------------------------------
extern "C" void kernel_launch(void* const* d_in, const int* in_sizes, int n_in,
                              void* d_out, int out_size, void* d_ws, size_t ws_size,
                              hipStream_t stream) {
  const float* feature = (const float*)d_in[0];
  const int* boxes = (const int*)d_in[1];
  const float* w1a = (const float*)d_in[2];
  const float* b1a = (const float*)d_in[3];
  const float* w1b = (const float*)d_in[4];
  const float* b1b = (const float*)d_in[5];
  const float* w2a = (const float*)d_in[6];
  const float* b2a = (const float*)d_in[7];
  const float* w2b = (const float*)d_in[8];
  const float* b2b = (const float*)d_in[9];
  const float* w3a = (const float*)d_in[10];
  const float* b3a = (const float*)d_in[11];
  const float* w3b = (const float*)d_in[12];
  const float* b3b = (const float*)d_in[13];
  const float* wDa = (const float*)d_in[14];
  const float* bDa = (const float*)d_in[15];
  const float* wDb = (const float*)d_in[16];
  const float* bDb = (const float*)d_in[17];
  const float* wF = (const float*)d_in[18];
  const float* bF = (const float*)d_in[19];

  const size_t WB = (size_t)2 * ((size_t)9 * 64 * 128 + 3 * 9 * 128 * 128 +
                                 (size_t)9 * 128 * 256 + 2 * 9 * 256 * 256 +
                                 2 * 256 * 256);
  const size_t PER_A = (size_t)832 * HP * WP * 2;
  int aloc = (ws_size >= 4 * PER_A + WB) ? 4 : 2;
  const int npixl = aloc * HWp;

  char* ws = (char*)d_ws;
  const size_t SZ128 = (size_t)aloc * HP * WP * 128 * 2;
  const size_t SZ256 = (size_t)aloc * HP * WP * 256 * 2;
  const size_t SZ64  = (size_t)aloc * HP * WP * 64 * 2;
  u16* X  = (u16*)(ws);
  u16* Y  = (u16*)(ws + SZ128);
  u16* S0 = (u16*)(ws + 2 * SZ128);
  u16* S1 = (u16*)(ws + 2 * SZ128 + SZ256);
  u16* in64 = (u16*)(ws + 2 * SZ128 + 2 * SZ256);
  u16* rp = (u16*)(ws + 2 * SZ128 + 2 * SZ256 + SZ64);

  const size_t o1a = 0;
  const size_t o1b = o1a + (size_t)9 * 64 * 128;
  const size_t o2a = o1b + (size_t)9 * 128 * 128;
  const size_t o2b = o2a + (size_t)9 * 128 * 128;
  const size_t o3a = o2b + (size_t)9 * 128 * 128;
  const size_t o3b = o3a + (size_t)9 * 128 * 256;
  const size_t oDa = o3b + (size_t)9 * 256 * 256;
  const size_t oDb = oDa + (size_t)9 * 256 * 256;
  const size_t oF = oDb + (size_t)256 * 256;

  auto rpk = [&](const float* wsrc, size_t off, int O, int I, int taps) {
    int total = O * I * taps;
    repack_w<<<(total + 255) / 256, 256, 0, stream>>>(wsrc, rp + off, O, I, taps);
  };
  rpk(w1a, o1a, 128, 64, 9);
  rpk(w1b, o1b, 128, 128, 9);
  rpk(w2a, o2a, 128, 128, 9);
  rpk(w2b, o2b, 128, 128, 9);
  rpk(w3a, o3a, 256, 128, 9);
  rpk(w3b, o3b, 256, 256, 9);
  rpk(wDa, oDa, 256, 256, 9);
  rpk(wDb, oDb, 256, 256, 1);
  rpk(wF, oF, 256, 256, 1);

  zero_border<64><<<(aloc * NB * 8 + 255) / 256, 256, 0, stream>>>(in64, aloc);
  zero_border<128><<<(aloc * NB * 16 + 255) / 256, 256, 0, stream>>>(X, aloc);
  zero_border<128><<<(aloc * NB * 16 + 255) / 256, 256, 0, stream>>>(Y, aloc);
  zero_border<256><<<(aloc * NB * 32 + 255) / 256, 256, 0, stream>>>(S1, aloc);

  const int G = npixl / 128;   // 550 or 1100
  const int G8 = npixl / 256;  // 275 or 550
  for (int a0 = 0; a0 < AG; a0 += aloc) {
    zero_border<256><<<(aloc * NB * 32 + 255) / 256, 256, 0, stream>>>(S0, aloc);

    convert_feat<<<aloc * H * 11, 256, 0, stream>>>(
        feature + (size_t)a0 * 64 * H * W, in64);

    conv_k<64, 128, 9><<<G, 256, 0, stream>>>(in64, rp + o1a, b1a, X, HP, WP, 1);
    conv_k<128, 128, 9><<<G, 256, 0, stream>>>(X, rp + o1b, b1b, Y, HP, WP, 1);
    conv_k<128, 128, 9><<<G, 256, 0, stream>>>(Y, rp + o2a, b2a, X, HP, WP, 1);
    conv_k<128, 128, 9><<<G, 256, 0, stream>>>(X, rp + o2b, b2b, Y, HP, WP, 1);
    conv8<128, 9><<<G8, 512, 0, stream>>>(Y, rp + o3a, b3a, S0, HP, WP, 1);
    conv8<256, 9><<<G8, 512, 0, stream>>>(S0, rp + o3b, b3b, S1, HP, WP, 1);
    conv8<256, 9><<<G8, 512, 0, stream>>>(S1, rp + oDa, bDa, S0, HP, WP, 1);
    conv8<256, 1><<<G8, 512, 0, stream>>>(S0, rp + oDb, bDb, S1, HP, WP, 1);
    conv8<256, 1><<<G8, 512, 0, stream>>>(S1, rp + oF, bF, S0, H, W, 0);

    pool_k<<<aloc * 50, 256, 0, stream>>>(S0, boxes + (size_t)a0 * 50 * 4,
                                          ((float*)d_out) + (size_t)a0 * 50 * 256);
  }
}

// Round 10
// 1224.091 us; speedup vs baseline: 1.4301x; 1.4249x over previous
//
#include <hip/hip_runtime.h>
#include <hip/hip_bf16.h>

typedef unsigned int u32;
typedef unsigned short u16;
typedef __attribute__((ext_vector_type(8))) short bf16x8;   // 8 bf16 = 4 VGPRs
typedef __attribute__((ext_vector_type(4))) float f32x4;

#define DEVI __device__ __forceinline__

constexpr int AG = 8, H = 100, W = 352, HP = 102, WP = 354;
constexpr int HWp = H * W;          // 35200
constexpr int NB = 2 * WP + 2 * H;  // 908 border pixels per agent

DEVI u16 f2bf(float f) {
  __hip_bfloat16 h = __float2bfloat16(f);
  return *reinterpret_cast<u16*>(&h);
}
DEVI float bf2f(u16 v) { return __uint_as_float(((u32)v) << 16); }

// interleaved channel order within each 32-block: stored 8v+j <-> logical
// {4v+j (j<4), 16+4v+(j-4) (j>=4)} so one 16B unit = one MFMA k-fragment.
DEVI int chperm(int j) { int v = j >> 3, r = j & 7; return (r < 4) ? 4 * v + r : 16 + 4 * v + (r - 4); }
DEVI int chlog(int c) { return (c & ~31) + chperm(c & 31); }

typedef __attribute__((address_space(1))) const u32 as1c_u32;
typedef __attribute__((address_space(3))) u32 as3_u32;
DEVI void gload16(const u16* g, u16* l) {
  __builtin_amdgcn_global_load_lds((as1c_u32*)(const void*)g, (as3_u32*)(void*)l, 16, 0, 0);
}

template <int N> DEVI void waitcnt_vm() {
  if constexpr (N == 0) asm volatile("s_waitcnt vmcnt(0)" ::: "memory");
  else if constexpr (N == 3) asm volatile("s_waitcnt vmcnt(3)" ::: "memory");
  else if constexpr (N == 4) asm volatile("s_waitcnt vmcnt(4)" ::: "memory");
  else asm volatile("s_waitcnt vmcnt(0)" ::: "memory");
}

// ---------------------------------------------------------------------------
// feature slice fp32 NCHW -> padded NHWC(permuted) bf16 interior, via LDS
// transpose. grid: aloc*H*11 blocks; block 256 thr; tile = (a,h) x 32w x 64c.
__global__ void convert_feat(const float* __restrict__ f, u16* __restrict__ dst) {
  __shared__ float t32[64][33];
  int blk = blockIdx.x;
  int wseg = blk % 11;
  int rest = blk / 11;
  int h = rest % H;
  int a = rest / H;
  int t = threadIdx.x;
  int wbase = wseg * 32;
  {
    int w = t & 31;
    int c0 = (t >> 5) * 8;
#pragma unroll
    for (int i = 0; i < 8; ++i) {
      int lc = c0 + i;
      t32[lc][w] = f[((size_t)(a * 64 + lc) * H + h) * W + wbase + w];
    }
  }
  __syncthreads();
  int p = t >> 3;
  int cs = (t & 7) * 8;
  u16 tmp[8];
#pragma unroll
  for (int j = 0; j < 8; ++j) {
    int c = cs + j;
    int lc = (c & 32) + chperm(c & 31);
    tmp[j] = f2bf(t32[lc][p]);
  }
  size_t ob = ((size_t)(a * HP + h + 1) * WP + (wbase + p + 1)) * 64 + cs;
  *reinterpret_cast<uint4*>(dst + ob) = *reinterpret_cast<uint4*>(tmp);
}

// zero the 1-pixel border of a padded NHWC buffer with C channels, nA agents
template <int C>
__global__ void zero_border(u16* __restrict__ buf, int nA) {
  constexpr int CH = C / 8;
  int idx = blockIdx.x * 256 + threadIdx.x;
  int pix = idx / CH;
  int cc = (idx - pix * CH) * 8;
  if (pix >= nA * NB) return;
  int a = pix / NB;
  int b = pix - a * NB;
  int h, w;
  if (b < WP) { h = 0; w = b; }
  else if (b < 2 * WP) { h = HP - 1; w = b - WP; }
  else {
    int bb = b - 2 * WP;
    int bb2 = (bb < H) ? bb : bb - H;
    h = 1 + bb2;
    w = (bb < H) ? 0 : (WP - 1);
  }
  size_t off = ((size_t)(a * HP + h) * WP + w) * C + cc;
  *reinterpret_cast<uint4*>(buf + off) = make_uint4(0u, 0u, 0u, 0u);
}

// w [O][I][kh][kw] fp32 -> rp[s=t*KB+kb][r:O][u:8][jj:8] bf16 with the LDS
// row-XOR swizzle baked in: stored (r,u) holds logical unit lu = u^(r&7).
__global__ void repack_w(const float* __restrict__ w, u16* __restrict__ rp,
                         int O, int I, int taps) {
  int idx = blockIdx.x * 256 + threadIdx.x;
  int total = O * I * taps;
  if (idx >= total) return;
  int jj = idx & 7;
  int u = (idx >> 3) & 7;
  int r = (idx >> 6) % O;
  int s = idx / (O * 64);
  int KB = I >> 6;
  int kb = s % KB;
  int t = s / KB;
  int lu = u ^ (r & 7);
  int g = lu & 3, j32 = lu >> 2;
  int cp = (jj < 4) ? 4 * g + jj : 16 + 4 * g + (jj - 4);
  int i = kb * 64 + j32 * 32 + cp;
  int o = (r & ~31) + chperm(r & 31);
  rp[idx] = f2bf(w[((size_t)o * I + i) * taps + t]);
}

// 1x1 weight [256][256] fp32 -> plain rp[kb32:8][r:256][g:4][jj:8] (no swizzle)
__global__ void repack_plain(const float* __restrict__ w, u16* __restrict__ rp) {
  int idx = blockIdx.x * 256 + threadIdx.x;  // 65536 total
  int jj = idx & 7;
  int g = (idx >> 3) & 3;
  int r = (idx >> 5) & 255;
  int kb = idx >> 13;
  int cp = (jj < 4) ? 4 * g + jj : 16 + 4 * g + (jj - 4);
  int i = kb * 32 + cp;
  int o = chlog(r);
  rp[idx] = f2bf(w[(size_t)o * 256 + i]);
}

// ---------------------------------------------------------------------------
// Round-6 proven conv kernel: BK=64, dbuf, half-split staging, counted vmcnt,
// setprio. 2 barriers per K-step.
template <int CIN, int BN, int TAPS>
__global__ __launch_bounds__(BN * 2, 2) void conv_k(
    const u16* __restrict__ in, const u16* __restrict__ wrp,
    const float* __restrict__ bias, u16* __restrict__ out,
    int outHp, int outWp, int outPad) {
  constexpr int BM = 128, BK = 64;
  constexpr int KB = CIN / BK;
  constexpr int KS = TAPS * KB;
  constexpr int NT = BN * 2;
  constexpr int WN = BN / 64;
  constexpr int ACH = 1024 / NT;
  constexpr int AH = ACH / 2;
  constexpr int BH = 2;
  constexpr int HALF = AH + BH;
  constexpr int ASZ = BM * BK;
  constexpr int BSZ = BN * BK;
  __shared__ u16 smem[2 * (ASZ + BSZ)];

  const int tid = threadIdx.x;
  const int lane = tid & 63;
  const int wid = tid >> 6;
  const int wr = wid / WN;
  const int wc = wid % WN;

  int nwg = gridDim.x;
  int orig = blockIdx.x;
  int q = nwg >> 3, r8 = nwg & 7;
  int xcd = orig & 7, pos = orig >> 3;
  int wg = (xcd < r8 ? xcd * (q + 1) : r8 * (q + 1) + (xcd - r8) * q) + pos;
  const int n0 = wg * BM;

  int aoff[ACH];
#pragma unroll
  for (int i = 0; i < ACH; ++i) {
    int c = tid + i * NT;
    int p = c >> 3, u = c & 7;
    int lu = u ^ (p & 7);
    int np2 = n0 + p;
    int a = np2 / HWp;
    int r1 = np2 - a * HWp;
    int h = r1 / W;
    int w = r1 - h * W;
    aoff[i] = ((a * HP + h + 1) * WP + (w + 1)) * CIN + lu * 8;
  }

  f32x4 acc[4][4];
#pragma unroll
  for (int m = 0; m < 4; ++m)
#pragma unroll
    for (int n = 0; n < 4; ++n) acc[m][n] = f32x4{0.f, 0.f, 0.f, 0.f};

  const int g = lane >> 4;
  const int arow = lane & 15;
  const int fk = arow & 7;

  auto stage = [&](int s, int h) {
    int par = s & 1;
    u16* Ad = smem + par * ASZ;
    u16* Bd = smem + 2 * ASZ + par * BSZ;
    int t = (TAPS == 1) ? 0 : s / KB;
    int kb = (TAPS == 1) ? s : s - t * KB;
    int doff = kb * BK + ((TAPS == 9) ? ((t / 3 - 1) * WP + (t % 3 - 1)) * CIN : 0);
    const u16* wtile = wrp + (size_t)s * BSZ;
#pragma unroll
    for (int i = h * AH; i < h * AH + AH; ++i)
      gload16(in + aoff[i] + doff, Ad + (tid + i * NT) * 8);
#pragma unroll
    for (int i = h * BH; i < h * BH + BH; ++i)
      gload16(wtile + (tid + i * NT) * 8, Bd + (tid + i * NT) * 8);
  };

  stage(0, 0);
  stage(0, 1);

  for (int s = 0; s < KS; ++s) {
    int par = s & 1;
    const u16* Ab = smem + par * ASZ;
    const u16* Bb = smem + 2 * ASZ + par * BSZ;
    if (s + 1 < KS) {
      stage(s + 1, 0);
      waitcnt_vm<HALF>();
    } else {
      waitcnt_vm<0>();
    }
    __builtin_amdgcn_s_barrier();

#pragma unroll
    for (int j = 0; j < 2; ++j) {
      bf16x8 af[4], bfr[4];
#pragma unroll
      for (int m = 0; m < 4; ++m)
        af[m] = *reinterpret_cast<const bf16x8*>(
            Ab + (wr * 64 + m * 16 + arow) * 64 + (((j * 4 + g) ^ fk) << 3));
#pragma unroll
      for (int n = 0; n < 4; ++n)
        bfr[n] = *reinterpret_cast<const bf16x8*>(
            Bb + (wc * 64 + n * 16 + arow) * 64 + (((j * 4 + g) ^ fk) << 3));
      __builtin_amdgcn_s_setprio(1);
#pragma unroll
      for (int m = 0; m < 4; ++m)
#pragma unroll
        for (int n = 0; n < 4; ++n)
          acc[m][n] = __builtin_amdgcn_mfma_f32_16x16x32_bf16(af[m], bfr[n], acc[m][n], 0, 0, 0);
      __builtin_amdgcn_s_setprio(0);
      if (j == 0 && s + 1 < KS) stage(s + 1, 1);
    }
    __builtin_amdgcn_s_barrier();
  }

  __syncthreads();
  float bs[4];
#pragma unroll
  for (int n = 0; n < 4; ++n) bs[n] = bias[chlog(wc * 64 + n * 16 + arow)];
  u16* et = smem + wid * 2048;
#pragma unroll
  for (int pp = 0; pp < 2; ++pp) {
    if (pp) __syncthreads();
#pragma unroll
    for (int mm = 0; mm < 2; ++mm) {
      int m = pp * 2 + mm;
#pragma unroll
      for (int rg = 0; rg < 4; ++rg) {
        int row = mm * 16 + g * 4 + rg;
#pragma unroll
        for (int n = 0; n < 4; ++n) {
          int col = (n * 16 + arow) ^ (g << 4);
          et[row * 64 + col] = f2bf(fmaxf(acc[m][n][rg] + bs[n], 0.f));
        }
      }
    }
    __syncthreads();
#pragma unroll
    for (int jj = 0; jj < 4; ++jj) {
      int p = jj * 8 + (lane >> 3);
      int un = lane & 7;
      int su = un ^ (((p >> 2) & 3) << 1);
      uint4 qv = *reinterpret_cast<const uint4*>(et + p * 64 + su * 8);
      int np2 = n0 + wr * 64 + pp * 32 + p;
      int a = np2 / HWp;
      int r1 = np2 - a * HWp;
      int h = r1 / W;
      int w = r1 - h * W;
      size_t ob = ((size_t)(a * outHp + h + outPad) * outWp + (w + outPad)) * BN +
                  wc * 64 + un * 8;
      *reinterpret_cast<uint4*>(out + ob) = qv;
    }
  }
}

// ---------------------------------------------------------------------------
// conv_k clone restricted to one box's pixels (Da layer: output needed only
// inside boxes). grid = nbox*2 blocks; block b: box b>>1, 128-px chunk b&1.
// Duplicate/overlap writes produce bitwise-identical values (benign).
__global__ __launch_bounds__(512, 2) void conv_box(
    const u16* __restrict__ in, const u16* __restrict__ wrp,
    const float* __restrict__ bias, u16* __restrict__ out,
    const int* __restrict__ boxes) {
  constexpr int CIN = 256, BN = 256, TAPS = 9;
  constexpr int BM = 128, BK = 64;
  constexpr int KB = CIN / BK;         // 4
  constexpr int KS = TAPS * KB;        // 36
  constexpr int NT = 512;
  constexpr int WN = 4;
  constexpr int ACH = 2, AH = 1, BH = 2, HALF = 3;
  constexpr int ASZ = BM * BK;
  constexpr int BSZ = BN * BK;
  __shared__ u16 smem[2 * (ASZ + BSZ)];

  const int blk = blockIdx.x;
  const int box = blk >> 1, c0 = blk & 1;
  const int* bx = boxes + box * 4;
  const int a = box / 50;
  const int l = bx[0], rr = bx[1], u0 = bx[2], d0 = bx[3];
  const int bw = rr - l;
  const int npx = bw * (d0 - u0);
  if (c0 * 128 >= npx) return;   // uniform block exit

  const int tid = threadIdx.x;
  const int lane = tid & 63;
  const int wid = tid >> 6;
  const int wr = wid / WN;
  const int wc = wid % WN;

  int aoff[ACH];
#pragma unroll
  for (int i = 0; i < ACH; ++i) {
    int c = tid + i * NT;
    int p = c >> 3, u = c & 7;
    int lu = u ^ (p & 7);
    int idx = c0 * 128 + p;
    if (idx >= npx) idx = npx - 1;
    int ph = u0 + idx / bw;
    int pw = l + idx % bw;
    aoff[i] = ((a * HP + ph + 1) * WP + (pw + 1)) * CIN + lu * 8;
  }

  f32x4 acc[4][4];
#pragma unroll
  for (int m = 0; m < 4; ++m)
#pragma unroll
    for (int n = 0; n < 4; ++n) acc[m][n] = f32x4{0.f, 0.f, 0.f, 0.f};

  const int g = lane >> 4;
  const int arow = lane & 15;
  const int fk = arow & 7;

  auto stage = [&](int s, int h) {
    int par = s & 1;
    u16* Ad = smem + par * ASZ;
    u16* Bd = smem + 2 * ASZ + par * BSZ;
    int t = s / KB;
    int kb = s - t * KB;
    int doff = kb * BK + ((t / 3 - 1) * WP + (t % 3 - 1)) * CIN;
    const u16* wtile = wrp + (size_t)s * BSZ;
#pragma unroll
    for (int i = h * AH; i < h * AH + AH; ++i)
      gload16(in + aoff[i] + doff, Ad + (tid + i * NT) * 8);
#pragma unroll
    for (int i = h * BH; i < h * BH + BH; ++i)
      gload16(wtile + (tid + i * NT) * 8, Bd + (tid + i * NT) * 8);
  };

  stage(0, 0);
  stage(0, 1);

  for (int s = 0; s < KS; ++s) {
    int par = s & 1;
    const u16* Ab = smem + par * ASZ;
    const u16* Bb = smem + 2 * ASZ + par * BSZ;
    if (s + 1 < KS) {
      stage(s + 1, 0);
      waitcnt_vm<HALF>();
    } else {
      waitcnt_vm<0>();
    }
    __builtin_amdgcn_s_barrier();

#pragma unroll
    for (int j = 0; j < 2; ++j) {
      bf16x8 af[4], bfr[4];
#pragma unroll
      for (int m = 0; m < 4; ++m)
        af[m] = *reinterpret_cast<const bf16x8*>(
            Ab + (wr * 64 + m * 16 + arow) * 64 + (((j * 4 + g) ^ fk) << 3));
#pragma unroll
      for (int n = 0; n < 4; ++n)
        bfr[n] = *reinterpret_cast<const bf16x8*>(
            Bb + (wc * 64 + n * 16 + arow) * 64 + (((j * 4 + g) ^ fk) << 3));
      __builtin_amdgcn_s_setprio(1);
#pragma unroll
      for (int m = 0; m < 4; ++m)
#pragma unroll
        for (int n = 0; n < 4; ++n)
          acc[m][n] = __builtin_amdgcn_mfma_f32_16x16x32_bf16(af[m], bfr[n], acc[m][n], 0, 0, 0);
      __builtin_amdgcn_s_setprio(0);
      if (j == 0 && s + 1 < KS) stage(s + 1, 1);
    }
    __builtin_amdgcn_s_barrier();
  }

  __syncthreads();
  float bs[4];
#pragma unroll
  for (int n = 0; n < 4; ++n) bs[n] = bias[chlog(wc * 64 + n * 16 + arow)];
  u16* et = smem + wid * 2048;
#pragma unroll
  for (int pp = 0; pp < 2; ++pp) {
    if (pp) __syncthreads();
#pragma unroll
    for (int mm = 0; mm < 2; ++mm) {
      int m = pp * 2 + mm;
#pragma unroll
      for (int rg = 0; rg < 4; ++rg) {
        int row = mm * 16 + g * 4 + rg;
#pragma unroll
        for (int n = 0; n < 4; ++n) {
          int col = (n * 16 + arow) ^ (g << 4);
          et[row * 64 + col] = f2bf(fmaxf(acc[m][n][rg] + bs[n], 0.f));
        }
      }
    }
    __syncthreads();
#pragma unroll
    for (int jj = 0; jj < 4; ++jj) {
      int p = jj * 8 + (lane >> 3);
      int un = lane & 7;
      int su = un ^ (((p >> 2) & 3) << 1);
      uint4 qv = *reinterpret_cast<const uint4*>(et + p * 64 + su * 8);
      int idx = c0 * 128 + wr * 64 + pp * 32 + p;
      if (idx >= npx) idx = npx - 1;  // dup writes, same value
      int ph = u0 + idx / bw;
      int pw = l + idx % bw;
      size_t ob = ((size_t)(a * HP + ph + 1) * WP + (pw + 1)) * BN + wc * 64 + un * 8;
      *reinterpret_cast<uint4*>(out + ob) = qv;
    }
  }
}

// ---------------------------------------------------------------------------
// Fused Db(1x1)+relu -> F(1x1)+relu -> box-mean. One block per box, 4 waves
// (64 out-ch each), 16-pixel chunks; weights plain-repacked, read from L2;
// intermediate xDb in swizzled LDS tile.
__global__ __launch_bounds__(256) void fuse_box(
    const u16* __restrict__ x, const u16* __restrict__ wDbp,
    const float* __restrict__ bDb, const u16* __restrict__ wFp,
    const float* __restrict__ bF, const int* __restrict__ boxes,
    float* __restrict__ desc) {
  __shared__ u16 xT[16 * 256];  // 8 KB
  const int blk = blockIdx.x;   // a*50 + k (slice-local)
  const int* bx = boxes + blk * 4;
  const int a = blk / 50;
  const int l = bx[0], rr = bx[1], u0 = bx[2], d0 = bx[3];
  const int bw = rr - l;
  const int npx = bw * (d0 - u0);
  const int nch = (npx + 15) >> 4;
  const int tid = threadIdx.x;
  const int lane = tid & 63;
  const int wc = tid >> 6;
  const int g = lane >> 4;
  const int arow = lane & 15;

  float b1[4], b2[4];
#pragma unroll
  for (int nf = 0; nf < 4; ++nf) {
    int ch = wc * 64 + nf * 16 + arow;
    b1[nf] = bDb[chlog(ch)];
    b2[nf] = bF[chlog(ch)];
  }
  float sums[4] = {0.f, 0.f, 0.f, 0.f};

  for (int ci = 0; ci < nch; ++ci) {
    // stage 1: A pixel = ci*16 + arow (clamped)
    int idx = ci * 16 + arow;
    if (idx >= npx) idx = npx - 1;
    int ph = u0 + idx / bw;
    int pw = l + idx % bw;
    const u16* ap = x + ((size_t)(a * HP + ph + 1) * WP + (pw + 1)) * 256;
    f32x4 a1[4];
#pragma unroll
    for (int nf = 0; nf < 4; ++nf) a1[nf] = f32x4{0.f, 0.f, 0.f, 0.f};
#pragma unroll
    for (int kb = 0; kb < 8; ++kb) {
      bf16x8 af = *reinterpret_cast<const bf16x8*>(ap + kb * 32 + g * 8);
#pragma unroll
      for (int nf = 0; nf < 4; ++nf) {
        bf16x8 bf_ = *reinterpret_cast<const bf16x8*>(
            wDbp + (((size_t)kb * 256 + wc * 64 + nf * 16 + arow) * 4 + g) * 8);
        a1[nf] = __builtin_amdgcn_mfma_f32_16x16x32_bf16(af, bf_, a1[nf], 0, 0, 0);
      }
    }
    if (ci) __syncthreads();  // previous chunk's xT reads done
    // relu+bias -> xT (pixel = g*4+rg, stored ch = wc*64+nf*16+arow, unit-swz)
#pragma unroll
    for (int nf = 0; nf < 4; ++nf)
#pragma unroll
      for (int rg = 0; rg < 4; ++rg) {
        int px = g * 4 + rg;
        int ch = wc * 64 + nf * 16 + arow;
        int siu = (ch >> 3) ^ (px & 7);
        xT[px * 256 + siu * 8 + (ch & 7)] = f2bf(fmaxf(a1[nf][rg] + b1[nf], 0.f));
      }
    __syncthreads();
    // stage 2
    f32x4 a2[4];
#pragma unroll
    for (int nf = 0; nf < 4; ++nf) a2[nf] = f32x4{0.f, 0.f, 0.f, 0.f};
#pragma unroll
    for (int kb = 0; kb < 8; ++kb) {
      int iu = kb * 4 + g;
      bf16x8 af2 = *reinterpret_cast<const bf16x8*>(
          xT + arow * 256 + (iu ^ (arow & 7)) * 8);
#pragma unroll
      for (int nf = 0; nf < 4; ++nf) {
        bf16x8 bf_ = *reinterpret_cast<const bf16x8*>(
            wFp + (((size_t)kb * 256 + wc * 64 + nf * 16 + arow) * 4 + g) * 8);
        a2[nf] = __builtin_amdgcn_mfma_f32_16x16x32_bf16(af2, bf_, a2[nf], 0, 0, 0);
      }
    }
    // relu+bias, mask invalid pixels, accumulate box sum
#pragma unroll
    for (int nf = 0; nf < 4; ++nf)
#pragma unroll
      for (int rg = 0; rg < 4; ++rg) {
        int pidx = ci * 16 + g * 4 + rg;
        if (pidx < npx) sums[nf] += fmaxf(a2[nf][rg] + b2[nf], 0.f);
      }
  }
  // reduce over the 4 pixel-groups (lanes ^16, ^32 share the same channel)
#pragma unroll
  for (int nf = 0; nf < 4; ++nf) {
    sums[nf] += __shfl_xor(sums[nf], 16, 64);
    sums[nf] += __shfl_xor(sums[nf], 32, 64);
  }
  if (g == 0) {
    float inv = 1.f / (float)npx;
#pragma unroll
    for (int nf = 0; nf < 4; ++nf) {
      int ch = wc * 64 + nf * 16 + arow;
      desc[(size_t)blk * 256 + chlog(ch)] = sums[nf] * inv;
    }
  }
}

// ---------------------------------------------------------------------------
extern "C" void kernel_launch(void* const* d_in, const int* in_sizes, int n_in,
                              void* d_out, int out_size, void* d_ws, size_t ws_size,
                              hipStream_t stream) {
  const float* feature = (const float*)d_in[0];
  const int* boxes = (const int*)d_in[1];
  const float* w1a = (const float*)d_in[2];
  const float* b1a = (const float*)d_in[3];
  const float* w1b = (const float*)d_in[4];
  const float* b1b = (const float*)d_in[5];
  const float* w2a = (const float*)d_in[6];
  const float* b2a = (const float*)d_in[7];
  const float* w2b = (const float*)d_in[8];
  const float* b2b = (const float*)d_in[9];
  const float* w3a = (const float*)d_in[10];
  const float* b3a = (const float*)d_in[11];
  const float* w3b = (const float*)d_in[12];
  const float* b3b = (const float*)d_in[13];
  const float* wDa = (const float*)d_in[14];
  const float* bDa = (const float*)d_in[15];
  const float* wDb = (const float*)d_in[16];
  const float* bDb = (const float*)d_in[17];
  const float* wF = (const float*)d_in[18];
  const float* bF = (const float*)d_in[19];

  // swizzled weights: 1a,1b,2a,2b,3a,3b,Da; plain: Db, F
  const size_t e1a = (size_t)9 * 64 * 128;
  const size_t e128 = (size_t)9 * 128 * 128;
  const size_t e3a = (size_t)9 * 128 * 256;
  const size_t e256 = (size_t)9 * 256 * 256;
  const size_t ePl = (size_t)256 * 256;
  const size_t WELEMS = e1a + 3 * e128 + e3a + 2 * e256 + 2 * ePl;
  const size_t WB = WELEMS * 2;
  const size_t PER_A = (size_t)832 * HP * WP * 2;
  int aloc = (ws_size >= 8 * PER_A + WB) ? 8 : (ws_size >= 4 * PER_A + WB) ? 4 : 2;
  const int npixl = aloc * HWp;

  char* ws = (char*)d_ws;
  const size_t SZ128 = (size_t)aloc * HP * WP * 128 * 2;
  const size_t SZ256 = (size_t)aloc * HP * WP * 256 * 2;
  const size_t SZ64  = (size_t)aloc * HP * WP * 64 * 2;
  u16* X  = (u16*)(ws);
  u16* Y  = (u16*)(ws + SZ128);
  u16* S0 = (u16*)(ws + 2 * SZ128);
  u16* S1 = (u16*)(ws + 2 * SZ128 + SZ256);
  u16* in64 = (u16*)(ws + 2 * SZ128 + 2 * SZ256);
  u16* rp = (u16*)(ws + 2 * SZ128 + 2 * SZ256 + SZ64);

  const size_t o1a = 0;
  const size_t o1b = o1a + e1a;
  const size_t o2a = o1b + e128;
  const size_t o2b = o2a + e128;
  const size_t o3a = o2b + e128;
  const size_t o3b = o3a + e3a;
  const size_t oDa = o3b + e256;
  const size_t oDbP = oDa + e256;
  const size_t oFP = oDbP + ePl;

  auto rpk = [&](const float* wsrc, size_t off, int O, int I, int taps) {
    int total = O * I * taps;
    repack_w<<<(total + 255) / 256, 256, 0, stream>>>(wsrc, rp + off, O, I, taps);
  };
  rpk(w1a, o1a, 128, 64, 9);
  rpk(w1b, o1b, 128, 128, 9);
  rpk(w2a, o2a, 128, 128, 9);
  rpk(w2b, o2b, 128, 128, 9);
  rpk(w3a, o3a, 256, 128, 9);
  rpk(w3b, o3b, 256, 256, 9);
  rpk(wDa, oDa, 256, 256, 9);
  repack_plain<<<256, 256, 0, stream>>>(wDb, rp + oDbP);
  repack_plain<<<256, 256, 0, stream>>>(wF, rp + oFP);

  // borders: never overwritten by any kernel -> zero once per call
  zero_border<64><<<(aloc * NB * 8 + 255) / 256, 256, 0, stream>>>(in64, aloc);
  zero_border<128><<<(aloc * NB * 16 + 255) / 256, 256, 0, stream>>>(X, aloc);
  zero_border<128><<<(aloc * NB * 16 + 255) / 256, 256, 0, stream>>>(Y, aloc);
  zero_border<256><<<(aloc * NB * 32 + 255) / 256, 256, 0, stream>>>(S0, aloc);
  zero_border<256><<<(aloc * NB * 32 + 255) / 256, 256, 0, stream>>>(S1, aloc);

  const int G = npixl / 128;
  for (int a0 = 0; a0 < AG; a0 += aloc) {
    convert_feat<<<aloc * H * 11, 256, 0, stream>>>(
        feature + (size_t)a0 * 64 * H * W, in64);

    conv_k<64, 128, 9><<<G, 256, 0, stream>>>(in64, rp + o1a, b1a, X, HP, WP, 1);
    conv_k<128, 128, 9><<<G, 256, 0, stream>>>(X, rp + o1b, b1b, Y, HP, WP, 1);
    conv_k<128, 128, 9><<<G, 256, 0, stream>>>(Y, rp + o2a, b2a, X, HP, WP, 1);
    conv_k<128, 128, 9><<<G, 256, 0, stream>>>(X, rp + o2b, b2b, Y, HP, WP, 1);
    conv_k<128, 256, 9><<<G, 512, 0, stream>>>(Y, rp + o3a, b3a, S0, HP, WP, 1);
    conv_k<256, 256, 9><<<G, 512, 0, stream>>>(S0, rp + o3b, b3b, S1, HP, WP, 1);
    // Da only at box pixels (output feeds only 1x1 convs + box pooling)
    conv_box<<<aloc * 50 * 2, 512, 0, stream>>>(
        S1, rp + oDa, bDa, S0, boxes + (size_t)a0 * 50 * 4);
    // fused Db+relu -> F+relu -> box-mean
    fuse_box<<<aloc * 50, 256, 0, stream>>>(
        S0, rp + oDbP, bDb, rp + oFP, bF, boxes + (size_t)a0 * 50 * 4,
        ((float*)d_out) + (size_t)a0 * 50 * 256);
  }
}

// Round 11
// 955.645 us; speedup vs baseline: 1.8319x; 1.2809x over previous
//
#include <hip/hip_runtime.h>
#include <hip/hip_bf16.h>

typedef unsigned int u32;
typedef unsigned short u16;
typedef __attribute__((ext_vector_type(8))) short bf16x8;   // 8 bf16 = 4 VGPRs
typedef __attribute__((ext_vector_type(4))) float f32x4;

#define DEVI __device__ __forceinline__

constexpr int AG = 8, H = 100, W = 352, HP = 102, WP = 354;
constexpr int HWp = H * W;          // 35200
constexpr int NB = 2 * WP + 2 * H;  // 908 border pixels per agent

DEVI u16 f2bf(float f) {
  __hip_bfloat16 h = __float2bfloat16(f);
  return *reinterpret_cast<u16*>(&h);
}
DEVI float bf2f(u16 v) { return __uint_as_float(((u32)v) << 16); }

// interleaved channel order within each 32-block: stored 8v+j <-> logical
// {4v+j (j<4), 16+4v+(j-4) (j>=4)} so one 16B unit = one MFMA k-fragment.
DEVI int chperm(int j) { int v = j >> 3, r = j & 7; return (r < 4) ? 4 * v + r : 16 + 4 * v + (r - 4); }
DEVI int chlog(int c) { return (c & ~31) + chperm(c & 31); }

typedef __attribute__((address_space(1))) const u32 as1c_u32;
typedef __attribute__((address_space(3))) u32 as3_u32;
DEVI void gload16(const u16* g, u16* l) {
  __builtin_amdgcn_global_load_lds((as1c_u32*)(const void*)g, (as3_u32*)(void*)l, 16, 0, 0);
}

template <int N> DEVI void waitcnt_vm() {
  if constexpr (N == 0) asm volatile("s_waitcnt vmcnt(0)" ::: "memory");
  else if constexpr (N == 3) asm volatile("s_waitcnt vmcnt(3)" ::: "memory");
  else if constexpr (N == 4) asm volatile("s_waitcnt vmcnt(4)" ::: "memory");
  else asm volatile("s_waitcnt vmcnt(0)" ::: "memory");
}

// ---------------------------------------------------------------------------
// feature slice fp32 NCHW -> padded NHWC(permuted) bf16 interior, via LDS
// transpose. grid: aloc*H*11 blocks; block 256 thr; tile = (a,h) x 32w x 64c.
__global__ void convert_feat(const float* __restrict__ f, u16* __restrict__ dst) {
  __shared__ float t32[64][33];
  int blk = blockIdx.x;
  int wseg = blk % 11;
  int rest = blk / 11;
  int h = rest % H;
  int a = rest / H;
  int t = threadIdx.x;
  int wbase = wseg * 32;
  {
    int w = t & 31;
    int c0 = (t >> 5) * 8;
#pragma unroll
    for (int i = 0; i < 8; ++i) {
      int lc = c0 + i;
      t32[lc][w] = f[((size_t)(a * 64 + lc) * H + h) * W + wbase + w];
    }
  }
  __syncthreads();
  int p = t >> 3;
  int cs = (t & 7) * 8;
  u16 tmp[8];
#pragma unroll
  for (int j = 0; j < 8; ++j) {
    int c = cs + j;
    int lc = (c & 32) + chperm(c & 31);
    tmp[j] = f2bf(t32[lc][p]);
  }
  size_t ob = ((size_t)(a * HP + h + 1) * WP + (wbase + p + 1)) * 64 + cs;
  *reinterpret_cast<uint4*>(dst + ob) = *reinterpret_cast<uint4*>(tmp);
}

// zero the 1-pixel border of a padded NHWC buffer with C channels, nA agents
template <int C>
__global__ void zero_border(u16* __restrict__ buf, int nA) {
  constexpr int CH = C / 8;
  int idx = blockIdx.x * 256 + threadIdx.x;
  int pix = idx / CH;
  int cc = (idx - pix * CH) * 8;
  if (pix >= nA * NB) return;
  int a = pix / NB;
  int b = pix - a * NB;
  int h, w;
  if (b < WP) { h = 0; w = b; }
  else if (b < 2 * WP) { h = HP - 1; w = b - WP; }
  else {
    int bb = b - 2 * WP;
    int bb2 = (bb < H) ? bb : bb - H;
    h = 1 + bb2;
    w = (bb < H) ? 0 : (WP - 1);
  }
  size_t off = ((size_t)(a * HP + h) * WP + w) * C + cc;
  *reinterpret_cast<uint4*>(buf + off) = make_uint4(0u, 0u, 0u, 0u);
}

// w [O][I][kh][kw] fp32 -> rp[s=t*KB+kb][r:O][u:8][jj:8] bf16 with the LDS
// row-XOR swizzle baked in: stored (r,u) holds logical unit lu = u^(r&7).
__global__ void repack_w(const float* __restrict__ w, u16* __restrict__ rp,
                         int O, int I, int taps) {
  int idx = blockIdx.x * 256 + threadIdx.x;
  int total = O * I * taps;
  if (idx >= total) return;
  int jj = idx & 7;
  int u = (idx >> 3) & 7;
  int r = (idx >> 6) % O;
  int s = idx / (O * 64);
  int KB = I >> 6;
  int kb = s % KB;
  int t = s / KB;
  int lu = u ^ (r & 7);
  int g = lu & 3, j32 = lu >> 2;
  int cp = (jj < 4) ? 4 * g + jj : 16 + 4 * g + (jj - 4);
  int i = kb * 64 + j32 * 32 + cp;
  int o = (r & ~31) + chperm(r & 31);
  rp[idx] = f2bf(w[((size_t)o * I + i) * taps + t]);
}

// 1x1 weight [256][256] fp32 -> plain rp[kb32:8][r:256][g:4][jj:8] (no swizzle)
__global__ void repack_plain(const float* __restrict__ w, u16* __restrict__ rp) {
  int idx = blockIdx.x * 256 + threadIdx.x;  // 65536 total
  int jj = idx & 7;
  int g = (idx >> 3) & 3;
  int r = (idx >> 5) & 255;
  int kb = idx >> 13;
  int cp = (jj < 4) ? 4 * g + jj : 16 + 4 * g + (jj - 4);
  int i = kb * 32 + cp;
  int o = chlog(r);
  rp[idx] = f2bf(w[(size_t)o * 256 + i]);
}

// ---------------------------------------------------------------------------
// Round-6 proven conv kernel: BK=64, dbuf, half-split staging, counted vmcnt,
// setprio. 2 barriers per K-step.
template <int CIN, int BN, int TAPS>
__global__ __launch_bounds__(BN * 2, 2) void conv_k(
    const u16* __restrict__ in, const u16* __restrict__ wrp,
    const float* __restrict__ bias, u16* __restrict__ out,
    int outHp, int outWp, int outPad) {
  constexpr int BM = 128, BK = 64;
  constexpr int KB = CIN / BK;
  constexpr int KS = TAPS * KB;
  constexpr int NT = BN * 2;
  constexpr int WN = BN / 64;
  constexpr int ACH = 1024 / NT;
  constexpr int AH = ACH / 2;
  constexpr int BH = 2;
  constexpr int HALF = AH + BH;
  constexpr int ASZ = BM * BK;
  constexpr int BSZ = BN * BK;
  __shared__ u16 smem[2 * (ASZ + BSZ)];

  const int tid = threadIdx.x;
  const int lane = tid & 63;
  const int wid = tid >> 6;
  const int wr = wid / WN;
  const int wc = wid % WN;

  int nwg = gridDim.x;
  int orig = blockIdx.x;
  int q = nwg >> 3, r8 = nwg & 7;
  int xcd = orig & 7, pos = orig >> 3;
  int wg = (xcd < r8 ? xcd * (q + 1) : r8 * (q + 1) + (xcd - r8) * q) + pos;
  const int n0 = wg * BM;

  int aoff[ACH];
#pragma unroll
  for (int i = 0; i < ACH; ++i) {
    int c = tid + i * NT;
    int p = c >> 3, u = c & 7;
    int lu = u ^ (p & 7);
    int np2 = n0 + p;
    int a = np2 / HWp;
    int r1 = np2 - a * HWp;
    int h = r1 / W;
    int w = r1 - h * W;
    aoff[i] = ((a * HP + h + 1) * WP + (w + 1)) * CIN + lu * 8;
  }

  f32x4 acc[4][4];
#pragma unroll
  for (int m = 0; m < 4; ++m)
#pragma unroll
    for (int n = 0; n < 4; ++n) acc[m][n] = f32x4{0.f, 0.f, 0.f, 0.f};

  const int g = lane >> 4;
  const int arow = lane & 15;
  const int fk = arow & 7;

  auto stage = [&](int s, int h) {
    int par = s & 1;
    u16* Ad = smem + par * ASZ;
    u16* Bd = smem + 2 * ASZ + par * BSZ;
    int t = (TAPS == 1) ? 0 : s / KB;
    int kb = (TAPS == 1) ? s : s - t * KB;
    int doff = kb * BK + ((TAPS == 9) ? ((t / 3 - 1) * WP + (t % 3 - 1)) * CIN : 0);
    const u16* wtile = wrp + (size_t)s * BSZ;
#pragma unroll
    for (int i = h * AH; i < h * AH + AH; ++i)
      gload16(in + aoff[i] + doff, Ad + (tid + i * NT) * 8);
#pragma unroll
    for (int i = h * BH; i < h * BH + BH; ++i)
      gload16(wtile + (tid + i * NT) * 8, Bd + (tid + i * NT) * 8);
  };

  stage(0, 0);
  stage(0, 1);

  for (int s = 0; s < KS; ++s) {
    int par = s & 1;
    const u16* Ab = smem + par * ASZ;
    const u16* Bb = smem + 2 * ASZ + par * BSZ;
    if (s + 1 < KS) {
      stage(s + 1, 0);
      waitcnt_vm<HALF>();
    } else {
      waitcnt_vm<0>();
    }
    __builtin_amdgcn_s_barrier();

#pragma unroll
    for (int j = 0; j < 2; ++j) {
      bf16x8 af[4], bfr[4];
#pragma unroll
      for (int m = 0; m < 4; ++m)
        af[m] = *reinterpret_cast<const bf16x8*>(
            Ab + (wr * 64 + m * 16 + arow) * 64 + (((j * 4 + g) ^ fk) << 3));
#pragma unroll
      for (int n = 0; n < 4; ++n)
        bfr[n] = *reinterpret_cast<const bf16x8*>(
            Bb + (wc * 64 + n * 16 + arow) * 64 + (((j * 4 + g) ^ fk) << 3));
      __builtin_amdgcn_s_setprio(1);
#pragma unroll
      for (int m = 0; m < 4; ++m)
#pragma unroll
        for (int n = 0; n < 4; ++n)
          acc[m][n] = __builtin_amdgcn_mfma_f32_16x16x32_bf16(af[m], bfr[n], acc[m][n], 0, 0, 0);
      __builtin_amdgcn_s_setprio(0);
      if (j == 0 && s + 1 < KS) stage(s + 1, 1);
    }
    __builtin_amdgcn_s_barrier();
  }

  __syncthreads();
  float bs[4];
#pragma unroll
  for (int n = 0; n < 4; ++n) bs[n] = bias[chlog(wc * 64 + n * 16 + arow)];
  u16* et = smem + wid * 2048;
#pragma unroll
  for (int pp = 0; pp < 2; ++pp) {
    if (pp) __syncthreads();
#pragma unroll
    for (int mm = 0; mm < 2; ++mm) {
      int m = pp * 2 + mm;
#pragma unroll
      for (int rg = 0; rg < 4; ++rg) {
        int row = mm * 16 + g * 4 + rg;
#pragma unroll
        for (int n = 0; n < 4; ++n) {
          int col = (n * 16 + arow) ^ (g << 4);
          et[row * 64 + col] = f2bf(fmaxf(acc[m][n][rg] + bs[n], 0.f));
        }
      }
    }
    __syncthreads();
#pragma unroll
    for (int jj = 0; jj < 4; ++jj) {
      int p = jj * 8 + (lane >> 3);
      int un = lane & 7;
      int su = un ^ (((p >> 2) & 3) << 1);
      uint4 qv = *reinterpret_cast<const uint4*>(et + p * 64 + su * 8);
      int np2 = n0 + wr * 64 + pp * 32 + p;
      int a = np2 / HWp;
      int r1 = np2 - a * HWp;
      int h = r1 / W;
      int w = r1 - h * W;
      size_t ob = ((size_t)(a * outHp + h + outPad) * outWp + (w + outPad)) * BN +
                  wc * 64 + un * 8;
      *reinterpret_cast<uint4*>(out + ob) = qv;
    }
  }
}

// ---------------------------------------------------------------------------
// Box-restricted 3x3 conv (BN=256, 512 thr): computes output only on the
// clamped (box+HALO) region. grid = nbox*MAXCH; block b: box b/MAXCH, 128-px
// chunk b%MAXCH. Duplicate/overlap writes are bitwise-identical (benign).
template <int CIN, int MAXCH, int HALO>
__global__ __launch_bounds__(512, 2) void conv_boxk(
    const u16* __restrict__ in, const u16* __restrict__ wrp,
    const float* __restrict__ bias, u16* __restrict__ out,
    const int* __restrict__ boxes) {
  constexpr int BN = 256, TAPS = 9;
  constexpr int BM = 128, BK = 64;
  constexpr int KB = CIN / BK;         // 2 or 4
  constexpr int KS = TAPS * KB;
  constexpr int NT = 512;
  constexpr int WN = 4;
  constexpr int ACH = 2, AH = 1, BH = 2, HALF = 3;
  constexpr int ASZ = BM * BK;
  constexpr int BSZ = BN * BK;
  __shared__ u16 smem[2 * (ASZ + BSZ)];

  const int blk = blockIdx.x;
  const int box = blk / MAXCH, c0 = blk % MAXCH;
  const int* bx = boxes + box * 4;
  const int a = box / 50;
  // clamped output region: rows [r0,r1) x cols [cl,cr)
  const int cl = max(bx[0] - HALO, 0);
  const int cr = min(bx[1] + HALO, W);
  const int r0 = max(bx[2] - HALO, 0);
  const int r1 = min(bx[3] + HALO, H);
  const int bw = cr - cl;
  const int npx = bw * (r1 - r0);
  if (c0 * 128 >= npx) return;   // uniform block exit

  const int tid = threadIdx.x;
  const int lane = tid & 63;
  const int wid = tid >> 6;
  const int wr = wid / WN;
  const int wc = wid % WN;

  int aoff[ACH];
#pragma unroll
  for (int i = 0; i < ACH; ++i) {
    int c = tid + i * NT;
    int p = c >> 3, u = c & 7;
    int lu = u ^ (p & 7);
    int idx = c0 * 128 + p;
    if (idx >= npx) idx = npx - 1;
    int ph = r0 + idx / bw;
    int pw = cl + idx % bw;
    aoff[i] = ((a * HP + ph + 1) * WP + (pw + 1)) * CIN + lu * 8;
  }

  f32x4 acc[4][4];
#pragma unroll
  for (int m = 0; m < 4; ++m)
#pragma unroll
    for (int n = 0; n < 4; ++n) acc[m][n] = f32x4{0.f, 0.f, 0.f, 0.f};

  const int g = lane >> 4;
  const int arow = lane & 15;
  const int fk = arow & 7;

  auto stage = [&](int s, int h) {
    int par = s & 1;
    u16* Ad = smem + par * ASZ;
    u16* Bd = smem + 2 * ASZ + par * BSZ;
    int t = s / KB;
    int kb = s - t * KB;
    int doff = kb * BK + ((t / 3 - 1) * WP + (t % 3 - 1)) * CIN;
    const u16* wtile = wrp + (size_t)s * BSZ;
#pragma unroll
    for (int i = h * AH; i < h * AH + AH; ++i)
      gload16(in + aoff[i] + doff, Ad + (tid + i * NT) * 8);
#pragma unroll
    for (int i = h * BH; i < h * BH + BH; ++i)
      gload16(wtile + (tid + i * NT) * 8, Bd + (tid + i * NT) * 8);
  };

  stage(0, 0);
  stage(0, 1);

  for (int s = 0; s < KS; ++s) {
    int par = s & 1;
    const u16* Ab = smem + par * ASZ;
    const u16* Bb = smem + 2 * ASZ + par * BSZ;
    if (s + 1 < KS) {
      stage(s + 1, 0);
      waitcnt_vm<HALF>();
    } else {
      waitcnt_vm<0>();
    }
    __builtin_amdgcn_s_barrier();

#pragma unroll
    for (int j = 0; j < 2; ++j) {
      bf16x8 af[4], bfr[4];
#pragma unroll
      for (int m = 0; m < 4; ++m)
        af[m] = *reinterpret_cast<const bf16x8*>(
            Ab + (wr * 64 + m * 16 + arow) * 64 + (((j * 4 + g) ^ fk) << 3));
#pragma unroll
      for (int n = 0; n < 4; ++n)
        bfr[n] = *reinterpret_cast<const bf16x8*>(
            Bb + (wc * 64 + n * 16 + arow) * 64 + (((j * 4 + g) ^ fk) << 3));
      __builtin_amdgcn_s_setprio(1);
#pragma unroll
      for (int m = 0; m < 4; ++m)
#pragma unroll
        for (int n = 0; n < 4; ++n)
          acc[m][n] = __builtin_amdgcn_mfma_f32_16x16x32_bf16(af[m], bfr[n], acc[m][n], 0, 0, 0);
      __builtin_amdgcn_s_setprio(0);
      if (j == 0 && s + 1 < KS) stage(s + 1, 1);
    }
    __builtin_amdgcn_s_barrier();
  }

  __syncthreads();
  float bs[4];
#pragma unroll
  for (int n = 0; n < 4; ++n) bs[n] = bias[chlog(wc * 64 + n * 16 + arow)];
  u16* et = smem + wid * 2048;
#pragma unroll
  for (int pp = 0; pp < 2; ++pp) {
    if (pp) __syncthreads();
#pragma unroll
    for (int mm = 0; mm < 2; ++mm) {
      int m = pp * 2 + mm;
#pragma unroll
      for (int rg = 0; rg < 4; ++rg) {
        int row = mm * 16 + g * 4 + rg;
#pragma unroll
        for (int n = 0; n < 4; ++n) {
          int col = (n * 16 + arow) ^ (g << 4);
          et[row * 64 + col] = f2bf(fmaxf(acc[m][n][rg] + bs[n], 0.f));
        }
      }
    }
    __syncthreads();
#pragma unroll
    for (int jj = 0; jj < 4; ++jj) {
      int p = jj * 8 + (lane >> 3);
      int un = lane & 7;
      int su = un ^ (((p >> 2) & 3) << 1);
      uint4 qv = *reinterpret_cast<const uint4*>(et + p * 64 + su * 8);
      int idx = c0 * 128 + wr * 64 + pp * 32 + p;
      if (idx >= npx) idx = npx - 1;  // dup writes, same value
      int ph = r0 + idx / bw;
      int pw = cl + idx % bw;
      size_t ob = ((size_t)(a * HP + ph + 1) * WP + (pw + 1)) * BN + wc * 64 + un * 8;
      *reinterpret_cast<uint4*>(out + ob) = qv;
    }
  }
}

// ---------------------------------------------------------------------------
// Fused Db(1x1)+relu -> F(1x1)+relu -> box-mean. One block per box, 4 waves
// (64 out-ch each), 16-pixel chunks; weights plain-repacked, read from L2;
// intermediate xDb in swizzled LDS tile.
__global__ __launch_bounds__(256) void fuse_box(
    const u16* __restrict__ x, const u16* __restrict__ wDbp,
    const float* __restrict__ bDb, const u16* __restrict__ wFp,
    const float* __restrict__ bF, const int* __restrict__ boxes,
    float* __restrict__ desc) {
  __shared__ u16 xT[16 * 256];  // 8 KB
  const int blk = blockIdx.x;   // a*50 + k (slice-local)
  const int* bx = boxes + blk * 4;
  const int a = blk / 50;
  const int l = bx[0], rr = bx[1], u0 = bx[2], d0 = bx[3];
  const int bw = rr - l;
  const int npx = bw * (d0 - u0);
  const int nch = (npx + 15) >> 4;
  const int tid = threadIdx.x;
  const int lane = tid & 63;
  const int wc = tid >> 6;
  const int g = lane >> 4;
  const int arow = lane & 15;

  float b1[4], b2[4];
#pragma unroll
  for (int nf = 0; nf < 4; ++nf) {
    int ch = wc * 64 + nf * 16 + arow;
    b1[nf] = bDb[chlog(ch)];
    b2[nf] = bF[chlog(ch)];
  }
  float sums[4] = {0.f, 0.f, 0.f, 0.f};

  for (int ci = 0; ci < nch; ++ci) {
    // stage 1: A pixel = ci*16 + arow (clamped)
    int idx = ci * 16 + arow;
    if (idx >= npx) idx = npx - 1;
    int ph = u0 + idx / bw;
    int pw = l + idx % bw;
    const u16* ap = x + ((size_t)(a * HP + ph + 1) * WP + (pw + 1)) * 256;
    f32x4 a1[4];
#pragma unroll
    for (int nf = 0; nf < 4; ++nf) a1[nf] = f32x4{0.f, 0.f, 0.f, 0.f};
#pragma unroll
    for (int kb = 0; kb < 8; ++kb) {
      bf16x8 af = *reinterpret_cast<const bf16x8*>(ap + kb * 32 + g * 8);
#pragma unroll
      for (int nf = 0; nf < 4; ++nf) {
        bf16x8 bf_ = *reinterpret_cast<const bf16x8*>(
            wDbp + (((size_t)kb * 256 + wc * 64 + nf * 16 + arow) * 4 + g) * 8);
        a1[nf] = __builtin_amdgcn_mfma_f32_16x16x32_bf16(af, bf_, a1[nf], 0, 0, 0);
      }
    }
    if (ci) __syncthreads();  // previous chunk's xT reads done
    // relu+bias -> xT (pixel = g*4+rg, stored ch = wc*64+nf*16+arow, unit-swz)
#pragma unroll
    for (int nf = 0; nf < 4; ++nf)
#pragma unroll
      for (int rg = 0; rg < 4; ++rg) {
        int px = g * 4 + rg;
        int ch = wc * 64 + nf * 16 + arow;
        int siu = (ch >> 3) ^ (px & 7);
        xT[px * 256 + siu * 8 + (ch & 7)] = f2bf(fmaxf(a1[nf][rg] + b1[nf], 0.f));
      }
    __syncthreads();
    // stage 2
    f32x4 a2[4];
#pragma unroll
    for (int nf = 0; nf < 4; ++nf) a2[nf] = f32x4{0.f, 0.f, 0.f, 0.f};
#pragma unroll
    for (int kb = 0; kb < 8; ++kb) {
      int iu = kb * 4 + g;
      bf16x8 af2 = *reinterpret_cast<const bf16x8*>(
          xT + arow * 256 + (iu ^ (arow & 7)) * 8);
#pragma unroll
      for (int nf = 0; nf < 4; ++nf) {
        bf16x8 bf_ = *reinterpret_cast<const bf16x8*>(
            wFp + (((size_t)kb * 256 + wc * 64 + nf * 16 + arow) * 4 + g) * 8);
        a2[nf] = __builtin_amdgcn_mfma_f32_16x16x32_bf16(af2, bf_, a2[nf], 0, 0, 0);
      }
    }
    // relu+bias, mask invalid pixels, accumulate box sum
#pragma unroll
    for (int nf = 0; nf < 4; ++nf)
#pragma unroll
      for (int rg = 0; rg < 4; ++rg) {
        int pidx = ci * 16 + g * 4 + rg;
        if (pidx < npx) sums[nf] += fmaxf(a2[nf][rg] + b2[nf], 0.f);
      }
  }
  // reduce over the 4 pixel-groups (lanes ^16, ^32 share the same channel)
#pragma unroll
  for (int nf = 0; nf < 4; ++nf) {
    sums[nf] += __shfl_xor(sums[nf], 16, 64);
    sums[nf] += __shfl_xor(sums[nf], 32, 64);
  }
  if (g == 0) {
    float inv = 1.f / (float)npx;
#pragma unroll
    for (int nf = 0; nf < 4; ++nf) {
      int ch = wc * 64 + nf * 16 + arow;
      desc[(size_t)blk * 256 + chlog(ch)] = sums[nf] * inv;
    }
  }
}

// ---------------------------------------------------------------------------
extern "C" void kernel_launch(void* const* d_in, const int* in_sizes, int n_in,
                              void* d_out, int out_size, void* d_ws, size_t ws_size,
                              hipStream_t stream) {
  const float* feature = (const float*)d_in[0];
  const int* boxes = (const int*)d_in[1];
  const float* w1a = (const float*)d_in[2];
  const float* b1a = (const float*)d_in[3];
  const float* w1b = (const float*)d_in[4];
  const float* b1b = (const float*)d_in[5];
  const float* w2a = (const float*)d_in[6];
  const float* b2a = (const float*)d_in[7];
  const float* w2b = (const float*)d_in[8];
  const float* b2b = (const float*)d_in[9];
  const float* w3a = (const float*)d_in[10];
  const float* b3a = (const float*)d_in[11];
  const float* w3b = (const float*)d_in[12];
  const float* b3b = (const float*)d_in[13];
  const float* wDa = (const float*)d_in[14];
  const float* bDa = (const float*)d_in[15];
  const float* wDb = (const float*)d_in[16];
  const float* bDb = (const float*)d_in[17];
  const float* wF = (const float*)d_in[18];
  const float* bF = (const float*)d_in[19];

  // swizzled weights: 1a,1b,2a,2b,3a,3b,Da; plain: Db, F
  const size_t e1a = (size_t)9 * 64 * 128;
  const size_t e128 = (size_t)9 * 128 * 128;
  const size_t e3a = (size_t)9 * 128 * 256;
  const size_t e256 = (size_t)9 * 256 * 256;
  const size_t ePl = (size_t)256 * 256;
  const size_t WELEMS = e1a + 3 * e128 + e3a + 2 * e256 + 2 * ePl;
  const size_t WB = WELEMS * 2;
  const size_t PER_A = (size_t)832 * HP * WP * 2;
  int aloc = (ws_size >= 8 * PER_A + WB) ? 8 : (ws_size >= 4 * PER_A + WB) ? 4 : 2;
  const int npixl = aloc * HWp;

  char* ws = (char*)d_ws;
  const size_t SZ128 = (size_t)aloc * HP * WP * 128 * 2;
  const size_t SZ256 = (size_t)aloc * HP * WP * 256 * 2;
  const size_t SZ64  = (size_t)aloc * HP * WP * 64 * 2;
  u16* X  = (u16*)(ws);
  u16* Y  = (u16*)(ws + SZ128);
  u16* S0 = (u16*)(ws + 2 * SZ128);
  u16* S1 = (u16*)(ws + 2 * SZ128 + SZ256);
  u16* in64 = (u16*)(ws + 2 * SZ128 + 2 * SZ256);
  u16* rp = (u16*)(ws + 2 * SZ128 + 2 * SZ256 + SZ64);

  const size_t o1a = 0;
  const size_t o1b = o1a + e1a;
  const size_t o2a = o1b + e128;
  const size_t o2b = o2a + e128;
  const size_t o3a = o2b + e128;
  const size_t o3b = o3a + e3a;
  const size_t oDa = o3b + e256;
  const size_t oDbP = oDa + e256;
  const size_t oFP = oDbP + ePl;

  auto rpk = [&](const float* wsrc, size_t off, int O, int I, int taps) {
    int total = O * I * taps;
    repack_w<<<(total + 255) / 256, 256, 0, stream>>>(wsrc, rp + off, O, I, taps);
  };
  rpk(w1a, o1a, 128, 64, 9);
  rpk(w1b, o1b, 128, 128, 9);
  rpk(w2a, o2a, 128, 128, 9);
  rpk(w2b, o2b, 128, 128, 9);
  rpk(w3a, o3a, 256, 128, 9);
  rpk(w3b, o3b, 256, 256, 9);
  rpk(wDa, oDa, 256, 256, 9);
  repack_plain<<<256, 256, 0, stream>>>(wDb, rp + oDbP);
  repack_plain<<<256, 256, 0, stream>>>(wF, rp + oFP);

  // borders: never overwritten by any kernel -> zero once per call
  zero_border<64><<<(aloc * NB * 8 + 255) / 256, 256, 0, stream>>>(in64, aloc);
  zero_border<128><<<(aloc * NB * 16 + 255) / 256, 256, 0, stream>>>(X, aloc);
  zero_border<128><<<(aloc * NB * 16 + 255) / 256, 256, 0, stream>>>(Y, aloc);
  zero_border<256><<<(aloc * NB * 32 + 255) / 256, 256, 0, stream>>>(S0, aloc);
  zero_border<256><<<(aloc * NB * 32 + 255) / 256, 256, 0, stream>>>(S1, aloc);

  const int G = npixl / 128;
  for (int a0 = 0; a0 < AG; a0 += aloc) {
    const int* bxs = boxes + (size_t)a0 * 50 * 4;
    convert_feat<<<aloc * H * 11, 256, 0, stream>>>(
        feature + (size_t)a0 * 64 * H * W, in64);

    conv_k<64, 128, 9><<<G, 256, 0, stream>>>(in64, rp + o1a, b1a, X, HP, WP, 1);
    conv_k<128, 128, 9><<<G, 256, 0, stream>>>(X, rp + o1b, b1b, Y, HP, WP, 1);
    conv_k<128, 128, 9><<<G, 256, 0, stream>>>(Y, rp + o2a, b2a, X, HP, WP, 1);
    conv_k<128, 128, 9><<<G, 256, 0, stream>>>(X, rp + o2b, b2b, Y, HP, WP, 1);
    // box-restricted tail: 3a at box+2, 3b at box+1, Da at box
    conv_boxk<128, 4, 2><<<aloc * 50 * 4, 512, 0, stream>>>(Y, rp + o3a, b3a, S0, bxs);
    conv_boxk<256, 3, 1><<<aloc * 50 * 3, 512, 0, stream>>>(S0, rp + o3b, b3b, S1, bxs);
    conv_boxk<256, 2, 0><<<aloc * 50 * 2, 512, 0, stream>>>(S1, rp + oDa, bDa, S0, bxs);
    // fused Db+relu -> F+relu -> box-mean
    fuse_box<<<aloc * 50, 256, 0, stream>>>(
        S0, rp + oDbP, bDb, rp + oFP, bF, bxs,
        ((float*)d_out) + (size_t)a0 * 50 * 256);
  }
}

// Round 12
// 791.531 us; speedup vs baseline: 2.2117x; 1.2073x over previous
//
#include <hip/hip_runtime.h>
#include <hip/hip_bf16.h>

typedef unsigned int u32;
typedef unsigned short u16;
typedef __attribute__((ext_vector_type(8))) short bf16x8;   // 8 bf16 = 4 VGPRs
typedef __attribute__((ext_vector_type(4))) float f32x4;

#define DEVI __device__ __forceinline__

constexpr int AG = 8, H = 100, W = 352, HP = 102, WP = 354;
constexpr int HWp = H * W;          // 35200
constexpr int NB = 2 * WP + 2 * H;  // 908 border pixels per agent

DEVI u16 f2bf(float f) {
  __hip_bfloat16 h = __float2bfloat16(f);
  return *reinterpret_cast<u16*>(&h);
}
DEVI float bf2f(u16 v) { return __uint_as_float(((u32)v) << 16); }

// interleaved channel order within each 32-block: stored 8v+j <-> logical
// {4v+j (j<4), 16+4v+(j-4) (j>=4)} so one 16B unit = one MFMA k-fragment.
DEVI int chperm(int j) { int v = j >> 3, r = j & 7; return (r < 4) ? 4 * v + r : 16 + 4 * v + (r - 4); }
DEVI int chlog(int c) { return (c & ~31) + chperm(c & 31); }

typedef __attribute__((address_space(1))) const u32 as1c_u32;
typedef __attribute__((address_space(3))) u32 as3_u32;
DEVI void gload16(const u16* g, u16* l) {
  __builtin_amdgcn_global_load_lds((as1c_u32*)(const void*)g, (as3_u32*)(void*)l, 16, 0, 0);
}

template <int N> DEVI void waitcnt_vm() {
  if constexpr (N == 0) asm volatile("s_waitcnt vmcnt(0)" ::: "memory");
  else if constexpr (N == 3) asm volatile("s_waitcnt vmcnt(3)" ::: "memory");
  else if constexpr (N == 4) asm volatile("s_waitcnt vmcnt(4)" ::: "memory");
  else asm volatile("s_waitcnt vmcnt(0)" ::: "memory");
}

// ---------------------------------------------------------------------------
// feature slice fp32 NCHW -> padded NHWC(permuted) bf16 interior, via LDS
// transpose. grid: aloc*H*11 blocks; block 256 thr; tile = (a,h) x 32w x 64c.
__global__ void convert_feat(const float* __restrict__ f, u16* __restrict__ dst) {
  __shared__ float t32[64][33];
  int blk = blockIdx.x;
  int wseg = blk % 11;
  int rest = blk / 11;
  int h = rest % H;
  int a = rest / H;
  int t = threadIdx.x;
  int wbase = wseg * 32;
  {
    int w = t & 31;
    int c0 = (t >> 5) * 8;
#pragma unroll
    for (int i = 0; i < 8; ++i) {
      int lc = c0 + i;
      t32[lc][w] = f[((size_t)(a * 64 + lc) * H + h) * W + wbase + w];
    }
  }
  __syncthreads();
  int p = t >> 3;
  int cs = (t & 7) * 8;
  u16 tmp[8];
#pragma unroll
  for (int j = 0; j < 8; ++j) {
    int c = cs + j;
    int lc = (c & 32) + chperm(c & 31);
    tmp[j] = f2bf(t32[lc][p]);
  }
  size_t ob = ((size_t)(a * HP + h + 1) * WP + (wbase + p + 1)) * 64 + cs;
  *reinterpret_cast<uint4*>(dst + ob) = *reinterpret_cast<uint4*>(tmp);
}

// zero the 1-pixel border of a padded NHWC buffer with C channels, nA agents
template <int C>
__global__ void zero_border(u16* __restrict__ buf, int nA) {
  constexpr int CH = C / 8;
  int idx = blockIdx.x * 256 + threadIdx.x;
  int pix = idx / CH;
  int cc = (idx - pix * CH) * 8;
  if (pix >= nA * NB) return;
  int a = pix / NB;
  int b = pix - a * NB;
  int h, w;
  if (b < WP) { h = 0; w = b; }
  else if (b < 2 * WP) { h = HP - 1; w = b - WP; }
  else {
    int bb = b - 2 * WP;
    int bb2 = (bb < H) ? bb : bb - H;
    h = 1 + bb2;
    w = (bb < H) ? 0 : (WP - 1);
  }
  size_t off = ((size_t)(a * HP + h) * WP + w) * C + cc;
  *reinterpret_cast<uint4*>(buf + off) = make_uint4(0u, 0u, 0u, 0u);
}

// w [O][I][kh][kw] fp32 -> rp[s=t*KB+kb][r:O][u:8][jj:8] bf16 with the LDS
// row-XOR swizzle baked in: stored (r,u) holds logical unit lu = u^(r&7).
__global__ void repack_w(const float* __restrict__ w, u16* __restrict__ rp,
                         int O, int I, int taps) {
  int idx = blockIdx.x * 256 + threadIdx.x;
  int total = O * I * taps;
  if (idx >= total) return;
  int jj = idx & 7;
  int u = (idx >> 3) & 7;
  int r = (idx >> 6) % O;
  int s = idx / (O * 64);
  int KB = I >> 6;
  int kb = s % KB;
  int t = s / KB;
  int lu = u ^ (r & 7);
  int g = lu & 3, j32 = lu >> 2;
  int cp = (jj < 4) ? 4 * g + jj : 16 + 4 * g + (jj - 4);
  int i = kb * 64 + j32 * 32 + cp;
  int o = (r & ~31) + chperm(r & 31);
  rp[idx] = f2bf(w[((size_t)o * I + i) * taps + t]);
}

// 1x1 weight [256][256] fp32 -> plain rp[kb32:8][r:256][g:4][jj:8] (no swizzle)
__global__ void repack_plain(const float* __restrict__ w, u16* __restrict__ rp) {
  int idx = blockIdx.x * 256 + threadIdx.x;  // 65536 total
  int jj = idx & 7;
  int g = (idx >> 3) & 3;
  int r = (idx >> 5) & 255;
  int kb = idx >> 13;
  int cp = (jj < 4) ? 4 * g + jj : 16 + 4 * g + (jj - 4);
  int i = kb * 32 + cp;
  int o = chlog(r);
  rp[idx] = f2bf(w[(size_t)o * 256 + i]);
}

// ---------------------------------------------------------------------------
// Box-restricted 3x3 conv, BN=128 column-split for occupancy (64 KB LDS ->
// 2 blocks/CU). Computes output on clamp(box+HALO). grid = nbox*MAXCH*NC;
// blk -> cb (cout block), chunk, box. Round-6 inner loop (dbuf, half-split
// staging, counted vmcnt, setprio). Duplicate writes bitwise-identical.
template <int CIN, int COUT, int MAXCH, int HALO>
__global__ __launch_bounds__(256, 2) void conv_boxk(
    const u16* __restrict__ in, const u16* __restrict__ wrp,
    const float* __restrict__ bias, u16* __restrict__ out,
    const int* __restrict__ boxes) {
  constexpr int BM = 128, BN = 128, BK = 64, TAPS = 9;
  constexpr int KB = CIN / BK;         // 1,2,4
  constexpr int KS = TAPS * KB;
  constexpr int NT = 256;
  constexpr int NC = COUT / BN;        // 1 or 2
  constexpr int ACH = 4, AH = 2, BH = 2, HALF = 4;
  constexpr int ASZ = BM * BK;
  constexpr int BSZ = BN * BK;
  __shared__ u16 smem[2 * (ASZ + BSZ)];  // 64 KB

  const int blk = blockIdx.x;
  const int cb = blk % NC;
  const int t1 = blk / NC;
  const int c0 = t1 % MAXCH;
  const int box = t1 / MAXCH;
  const int* bx = boxes + box * 4;
  const int a = box / 50;
  const int cl = max(bx[0] - HALO, 0);
  const int cr = min(bx[1] + HALO, W);
  const int r0 = max(bx[2] - HALO, 0);
  const int r1 = min(bx[3] + HALO, H);
  const int bw = cr - cl;
  const int npx = bw * (r1 - r0);
  if (c0 * 128 >= npx) return;   // uniform block exit

  const int tid = threadIdx.x;
  const int lane = tid & 63;
  const int wid = tid >> 6;
  const int wr = wid >> 1;
  const int wc = wid & 1;

  int aoff[ACH];
#pragma unroll
  for (int i = 0; i < ACH; ++i) {
    int c = tid + i * NT;
    int p = c >> 3, u = c & 7;
    int lu = u ^ (p & 7);
    int idx = c0 * 128 + p;
    if (idx >= npx) idx = npx - 1;
    int ph = r0 + idx / bw;
    int pw = cl + idx % bw;
    aoff[i] = ((a * HP + ph + 1) * WP + (pw + 1)) * CIN + lu * 8;
  }

  f32x4 acc[4][4];
#pragma unroll
  for (int m = 0; m < 4; ++m)
#pragma unroll
    for (int n = 0; n < 4; ++n) acc[m][n] = f32x4{0.f, 0.f, 0.f, 0.f};

  const int g = lane >> 4;
  const int arow = lane & 15;
  const int fk = arow & 7;

  auto stage = [&](int s, int h) {
    int par = s & 1;
    u16* Ad = smem + par * ASZ;
    u16* Bd = smem + 2 * ASZ + par * BSZ;
    int t = s / KB;
    int kb = s - t * KB;
    int doff = kb * BK + ((t / 3 - 1) * WP + (t % 3 - 1)) * CIN;
    const u16* wtile = wrp + (size_t)s * (COUT * BK) + cb * BSZ;
#pragma unroll
    for (int i = h * AH; i < h * AH + AH; ++i)
      gload16(in + aoff[i] + doff, Ad + (tid + i * NT) * 8);
#pragma unroll
    for (int i = h * BH; i < h * BH + BH; ++i)
      gload16(wtile + (tid + i * NT) * 8, Bd + (tid + i * NT) * 8);
  };

  stage(0, 0);
  stage(0, 1);

  for (int s = 0; s < KS; ++s) {
    int par = s & 1;
    const u16* Ab = smem + par * ASZ;
    const u16* Bb = smem + 2 * ASZ + par * BSZ;
    if (s + 1 < KS) {
      stage(s + 1, 0);
      waitcnt_vm<HALF>();
    } else {
      waitcnt_vm<0>();
    }
    __builtin_amdgcn_s_barrier();

#pragma unroll
    for (int j = 0; j < 2; ++j) {
      bf16x8 af[4], bfr[4];
#pragma unroll
      for (int m = 0; m < 4; ++m)
        af[m] = *reinterpret_cast<const bf16x8*>(
            Ab + (wr * 64 + m * 16 + arow) * 64 + (((j * 4 + g) ^ fk) << 3));
#pragma unroll
      for (int n = 0; n < 4; ++n)
        bfr[n] = *reinterpret_cast<const bf16x8*>(
            Bb + (wc * 64 + n * 16 + arow) * 64 + (((j * 4 + g) ^ fk) << 3));
      __builtin_amdgcn_s_setprio(1);
#pragma unroll
      for (int m = 0; m < 4; ++m)
#pragma unroll
        for (int n = 0; n < 4; ++n)
          acc[m][n] = __builtin_amdgcn_mfma_f32_16x16x32_bf16(af[m], bfr[n], acc[m][n], 0, 0, 0);
      __builtin_amdgcn_s_setprio(0);
      if (j == 0 && s + 1 < KS) stage(s + 1, 1);
    }
    __builtin_amdgcn_s_barrier();
  }

  __syncthreads();
  float bs[4];
#pragma unroll
  for (int n = 0; n < 4; ++n) bs[n] = bias[chlog(cb * BN + wc * 64 + n * 16 + arow)];
  u16* et = smem + wid * 2048;
#pragma unroll
  for (int pp = 0; pp < 2; ++pp) {
    if (pp) __syncthreads();
#pragma unroll
    for (int mm = 0; mm < 2; ++mm) {
      int m = pp * 2 + mm;
#pragma unroll
      for (int rg = 0; rg < 4; ++rg) {
        int row = mm * 16 + g * 4 + rg;
#pragma unroll
        for (int n = 0; n < 4; ++n) {
          int col = (n * 16 + arow) ^ (g << 4);
          et[row * 64 + col] = f2bf(fmaxf(acc[m][n][rg] + bs[n], 0.f));
        }
      }
    }
    __syncthreads();
#pragma unroll
    for (int jj = 0; jj < 4; ++jj) {
      int p = jj * 8 + (lane >> 3);
      int un = lane & 7;
      int su = un ^ (((p >> 2) & 3) << 1);
      uint4 qv = *reinterpret_cast<const uint4*>(et + p * 64 + su * 8);
      int idx = c0 * 128 + wr * 64 + pp * 32 + p;
      if (idx >= npx) idx = npx - 1;  // dup writes, same value
      int ph = r0 + idx / bw;
      int pw = cl + idx % bw;
      size_t ob = ((size_t)(a * HP + ph + 1) * WP + (pw + 1)) * COUT +
                  cb * BN + wc * 64 + un * 8;
      *reinterpret_cast<uint4*>(out + ob) = qv;
    }
  }
}

// ---------------------------------------------------------------------------
// Fused Db(1x1)+relu -> F(1x1)+relu -> box-mean. One block per box, 4 waves
// (64 out-ch each), 16-pixel chunks; weights plain-repacked, read from L2;
// intermediate xDb in swizzled LDS tile.
__global__ __launch_bounds__(256) void fuse_box(
    const u16* __restrict__ x, const u16* __restrict__ wDbp,
    const float* __restrict__ bDb, const u16* __restrict__ wFp,
    const float* __restrict__ bF, const int* __restrict__ boxes,
    float* __restrict__ desc) {
  __shared__ u16 xT[16 * 256];  // 8 KB
  const int blk = blockIdx.x;   // a*50 + k (slice-local)
  const int* bx = boxes + blk * 4;
  const int a = blk / 50;
  const int l = bx[0], rr = bx[1], u0 = bx[2], d0 = bx[3];
  const int bw = rr - l;
  const int npx = bw * (d0 - u0);
  const int nch = (npx + 15) >> 4;
  const int tid = threadIdx.x;
  const int lane = tid & 63;
  const int wc = tid >> 6;
  const int g = lane >> 4;
  const int arow = lane & 15;

  float b1[4], b2[4];
#pragma unroll
  for (int nf = 0; nf < 4; ++nf) {
    int ch = wc * 64 + nf * 16 + arow;
    b1[nf] = bDb[chlog(ch)];
    b2[nf] = bF[chlog(ch)];
  }
  float sums[4] = {0.f, 0.f, 0.f, 0.f};

  for (int ci = 0; ci < nch; ++ci) {
    // stage 1: A pixel = ci*16 + arow (clamped)
    int idx = ci * 16 + arow;
    if (idx >= npx) idx = npx - 1;
    int ph = u0 + idx / bw;
    int pw = l + idx % bw;
    const u16* ap = x + ((size_t)(a * HP + ph + 1) * WP + (pw + 1)) * 256;
    f32x4 a1[4];
#pragma unroll
    for (int nf = 0; nf < 4; ++nf) a1[nf] = f32x4{0.f, 0.f, 0.f, 0.f};
#pragma unroll
    for (int kb = 0; kb < 8; ++kb) {
      bf16x8 af = *reinterpret_cast<const bf16x8*>(ap + kb * 32 + g * 8);
#pragma unroll
      for (int nf = 0; nf < 4; ++nf) {
        bf16x8 bf_ = *reinterpret_cast<const bf16x8*>(
            wDbp + (((size_t)kb * 256 + wc * 64 + nf * 16 + arow) * 4 + g) * 8);
        a1[nf] = __builtin_amdgcn_mfma_f32_16x16x32_bf16(af, bf_, a1[nf], 0, 0, 0);
      }
    }
    if (ci) __syncthreads();  // previous chunk's xT reads done
    // relu+bias -> xT (pixel = g*4+rg, stored ch = wc*64+nf*16+arow, unit-swz)
#pragma unroll
    for (int nf = 0; nf < 4; ++nf)
#pragma unroll
      for (int rg = 0; rg < 4; ++rg) {
        int px = g * 4 + rg;
        int ch = wc * 64 + nf * 16 + arow;
        int siu = (ch >> 3) ^ (px & 7);
        xT[px * 256 + siu * 8 + (ch & 7)] = f2bf(fmaxf(a1[nf][rg] + b1[nf], 0.f));
      }
    __syncthreads();
    // stage 2
    f32x4 a2[4];
#pragma unroll
    for (int nf = 0; nf < 4; ++nf) a2[nf] = f32x4{0.f, 0.f, 0.f, 0.f};
#pragma unroll
    for (int kb = 0; kb < 8; ++kb) {
      int iu = kb * 4 + g;
      bf16x8 af2 = *reinterpret_cast<const bf16x8*>(
          xT + arow * 256 + (iu ^ (arow & 7)) * 8);
#pragma unroll
      for (int nf = 0; nf < 4; ++nf) {
        bf16x8 bf_ = *reinterpret_cast<const bf16x8*>(
            wFp + (((size_t)kb * 256 + wc * 64 + nf * 16 + arow) * 4 + g) * 8);
        a2[nf] = __builtin_amdgcn_mfma_f32_16x16x32_bf16(af2, bf_, a2[nf], 0, 0, 0);
      }
    }
    // relu+bias, mask invalid pixels, accumulate box sum
#pragma unroll
    for (int nf = 0; nf < 4; ++nf)
#pragma unroll
      for (int rg = 0; rg < 4; ++rg) {
        int pidx = ci * 16 + g * 4 + rg;
        if (pidx < npx) sums[nf] += fmaxf(a2[nf][rg] + b2[nf], 0.f);
      }
  }
  // reduce over the 4 pixel-groups (lanes ^16, ^32 share the same channel)
#pragma unroll
  for (int nf = 0; nf < 4; ++nf) {
    sums[nf] += __shfl_xor(sums[nf], 16, 64);
    sums[nf] += __shfl_xor(sums[nf], 32, 64);
  }
  if (g == 0) {
    float inv = 1.f / (float)npx;
#pragma unroll
    for (int nf = 0; nf < 4; ++nf) {
      int ch = wc * 64 + nf * 16 + arow;
      desc[(size_t)blk * 256 + chlog(ch)] = sums[nf] * inv;
    }
  }
}

// ---------------------------------------------------------------------------
extern "C" void kernel_launch(void* const* d_in, const int* in_sizes, int n_in,
                              void* d_out, int out_size, void* d_ws, size_t ws_size,
                              hipStream_t stream) {
  const float* feature = (const float*)d_in[0];
  const int* boxes = (const int*)d_in[1];
  const float* w1a = (const float*)d_in[2];
  const float* b1a = (const float*)d_in[3];
  const float* w1b = (const float*)d_in[4];
  const float* b1b = (const float*)d_in[5];
  const float* w2a = (const float*)d_in[6];
  const float* b2a = (const float*)d_in[7];
  const float* w2b = (const float*)d_in[8];
  const float* b2b = (const float*)d_in[9];
  const float* w3a = (const float*)d_in[10];
  const float* b3a = (const float*)d_in[11];
  const float* w3b = (const float*)d_in[12];
  const float* b3b = (const float*)d_in[13];
  const float* wDa = (const float*)d_in[14];
  const float* bDa = (const float*)d_in[15];
  const float* wDb = (const float*)d_in[16];
  const float* bDb = (const float*)d_in[17];
  const float* wF = (const float*)d_in[18];
  const float* bF = (const float*)d_in[19];

  // swizzled weights: 1a,1b,2a,2b,3a,3b,Da; plain: Db, F
  const size_t e1a = (size_t)9 * 64 * 128;
  const size_t e128 = (size_t)9 * 128 * 128;
  const size_t e3a = (size_t)9 * 128 * 256;
  const size_t e256 = (size_t)9 * 256 * 256;
  const size_t ePl = (size_t)256 * 256;
  const size_t WELEMS = e1a + 3 * e128 + e3a + 2 * e256 + 2 * ePl;
  const size_t WB = WELEMS * 2;
  const size_t PER_A = (size_t)832 * HP * WP * 2;
  int aloc = (ws_size >= 8 * PER_A + WB) ? 8 : (ws_size >= 4 * PER_A + WB) ? 4 : 2;
  const int npixl = aloc * HWp;

  char* ws = (char*)d_ws;
  const size_t SZ128 = (size_t)aloc * HP * WP * 128 * 2;
  const size_t SZ256 = (size_t)aloc * HP * WP * 256 * 2;
  const size_t SZ64  = (size_t)aloc * HP * WP * 64 * 2;
  u16* X  = (u16*)(ws);
  u16* Y  = (u16*)(ws + SZ128);
  u16* S0 = (u16*)(ws + 2 * SZ128);
  u16* S1 = (u16*)(ws + 2 * SZ128 + SZ256);
  u16* in64 = (u16*)(ws + 2 * SZ128 + 2 * SZ256);
  u16* rp = (u16*)(ws + 2 * SZ128 + 2 * SZ256 + SZ64);

  const size_t o1a = 0;
  const size_t o1b = o1a + e1a;
  const size_t o2a = o1b + e128;
  const size_t o2b = o2a + e128;
  const size_t o3a = o2b + e128;
  const size_t o3b = o3a + e3a;
  const size_t oDa = o3b + e256;
  const size_t oDbP = oDa + e256;
  const size_t oFP = oDbP + ePl;

  auto rpk = [&](const float* wsrc, size_t off, int O, int I, int taps) {
    int total = O * I * taps;
    repack_w<<<(total + 255) / 256, 256, 0, stream>>>(wsrc, rp + off, O, I, taps);
  };
  rpk(w1a, o1a, 128, 64, 9);
  rpk(w1b, o1b, 128, 128, 9);
  rpk(w2a, o2a, 128, 128, 9);
  rpk(w2b, o2b, 128, 128, 9);
  rpk(w3a, o3a, 256, 128, 9);
  rpk(w3b, o3b, 256, 256, 9);
  rpk(wDa, oDa, 256, 256, 9);
  repack_plain<<<256, 256, 0, stream>>>(wDb, rp + oDbP);
  repack_plain<<<256, 256, 0, stream>>>(wF, rp + oFP);

  // borders: never overwritten by any kernel -> zero once per call
  zero_border<64><<<(aloc * NB * 8 + 255) / 256, 256, 0, stream>>>(in64, aloc);
  zero_border<128><<<(aloc * NB * 16 + 255) / 256, 256, 0, stream>>>(X, aloc);
  zero_border<128><<<(aloc * NB * 16 + 255) / 256, 256, 0, stream>>>(Y, aloc);
  zero_border<256><<<(aloc * NB * 32 + 255) / 256, 256, 0, stream>>>(S0, aloc);
  zero_border<256><<<(aloc * NB * 32 + 255) / 256, 256, 0, stream>>>(S1, aloc);

  const int nbox = aloc * 50;
  for (int a0 = 0; a0 < AG; a0 += aloc) {
    const int* bxs = boxes + (size_t)a0 * 50 * 4;
    convert_feat<<<aloc * H * 11, 256, 0, stream>>>(
        feature + (size_t)a0 * 64 * H * W, in64);

    // box-restricted chain with growing halos: 1a@box+6 ... Da@box+0.
    // Each layer's p+-1 reads fall inside the next-larger fresh halo (or the
    // once-zeroed padded border). Duplicate writes are bitwise-identical.
    conv_boxk<64, 128, 7, 6><<<nbox * 7, 256, 0, stream>>>(in64, rp + o1a, b1a, X, bxs);
    conv_boxk<128, 128, 6, 5><<<nbox * 6, 256, 0, stream>>>(X, rp + o1b, b1b, Y, bxs);
    conv_boxk<128, 128, 5, 4><<<nbox * 5, 256, 0, stream>>>(Y, rp + o2a, b2a, X, bxs);
    conv_boxk<128, 128, 4, 3><<<nbox * 4, 256, 0, stream>>>(X, rp + o2b, b2b, Y, bxs);
    conv_boxk<128, 256, 4, 2><<<nbox * 4 * 2, 256, 0, stream>>>(Y, rp + o3a, b3a, S0, bxs);
    conv_boxk<256, 256, 3, 1><<<nbox * 3 * 2, 256, 0, stream>>>(S0, rp + o3b, b3b, S1, bxs);
    conv_boxk<256, 256, 2, 0><<<nbox * 2 * 2, 256, 0, stream>>>(S1, rp + oDa, bDa, S0, bxs);
    // fused Db+relu -> F+relu -> box-mean
    fuse_box<<<nbox, 256, 0, stream>>>(
        S0, rp + oDbP, bDb, rp + oFP, bF, bxs,
        ((float*)d_out) + (size_t)a0 * 50 * 256);
  }
}